// Round 12
// baseline (613.907 us; speedup 1.0000x reference)
//
#include <hip/hip_runtime.h>
#include <hip/hip_bf16.h>

typedef __hip_bfloat16 bf16;
#define TPB 256

typedef __attribute__((ext_vector_type(8))) short s8v;
typedef __attribute__((ext_vector_type(4))) short s4v;
typedef __attribute__((ext_vector_type(4))) float f4v;

__device__ inline void wred2(float& a, float& b) {
#pragma unroll
    for (int o = 32; o > 0; o >>= 1) {
        a += __shfl_down(a, o, 64);
        b += __shfl_down(b, o, 64);
    }
}

// BN coeff setup: sc/sh for 8 channels starting at ch0 within a stats region.
__device__ inline void bnco(const float* st, const float* g, const float* b,
                            float invN, int ch0, float* sc, float* sh) {
#pragma unroll
    for (int j = 0; j < 8; ++j) {
        int ch = ch0 + j;
        float mean = st[2 * ch] * invN;
        float var  = st[2 * ch + 1] * invN - mean * mean;
        sc[j] = rsqrtf(var + 1e-5f) * g[ch];
        sh[j] = b[ch] - mean * sc[j];
    }
}
// apply BN+ReLU to a 16B bf16x8 chunk (u) -> packed o
__device__ inline void bnap(const uint4& u, const float* sc, const float* sh,
                            bf16* o) {
    const unsigned short* s = (const unsigned short*)&u;
#pragma unroll
    for (int j = 0; j < 8; ++j) {
        float v = __uint_as_float((unsigned)s[j] << 16);
        v = v * sc[j] + sh[j];
        o[j] = __float2bfloat16(v > 0.f ? v : 0.f);
    }
}

// ---------------------------------------------------------------------------
// Repack bodies as device functions (virtual block index vb), merged into a
// single init_all_k dispatch. Stats stay in the prt+sumcol path (round-10
// A/B: same-address atomicAdd stats throttled conv0 ~2x).
// ---------------------------------------------------------------------------
__device__ inline void rep_wbc(const float* __restrict__ w,
                               bf16* __restrict__ wb,
                               int OCR, int IC, int KK, int NT, int vb)
{
    int idx = vb * TPB + (int)threadIdx.x;
    int tot = KK * NT * 512;
    if (idx >= tot) return;
    int j = idx & 7;
    int l = (idx >> 3) & 63;
    int rest = idx >> 9;
    int nt = rest % NT;
    int kk = rest / NT;
    int n = nt * 16 + (l & 15);
    int k = kk * 32 + (l >> 4) * 8 + j;
    int tap = k / IC, ci = k % IC;
    float v = (n < OCR && tap < 27) ? w[(n * IC + ci) * 27 + tap] : 0.f;
    wb[idx] = __float2bfloat16(v);
}

__device__ inline void rep_wb(const float* __restrict__ w,
                              bf16* __restrict__ wb,
                              int OCR, int IC, int KC, int NT, int vb)
{
    int idx = vb * TPB + (int)threadIdx.x;
    int tot = 27 * KC * NT * 512;
    if (idx >= tot) return;
    int j = idx & 7;
    int l = (idx >> 3) & 63;
    int rest = idx >> 9;
    int nt = rest % NT;
    int kc = (rest / NT) % KC;
    int kt = rest / (NT * KC);
    int n = nt * 16 + (l & 15);
    int k = kc * 32 + (l >> 4) * 8 + j;
    float v = (n < OCR && k < IC) ? w[(n * IC + k) * 27 + kt] : 0.f;
    wb[idx] = __float2bfloat16(v);
}

// Final-conv compact weights for K=16 MFMA: wc16[tap 27][half 2][n 2][ci 16].
__device__ inline void rep_wc16(const float* __restrict__ w,
                                bf16* __restrict__ wc, int vb)
{
    int idx = vb * TPB + (int)threadIdx.x;
    if (idx >= 3456) return;
    int ci = idx & 15;
    int n = (idx >> 4) & 1;
    int h = (idx >> 5) & 1;
    int tap = idx >> 6;
    wc[idx] = __float2bfloat16(w[(n * 32 + h * 16 + ci) * 27 + tap]);
}

__global__ __launch_bounds__(TPB) void init_all_k(
    const float* wt1, const float* wt2, const float* wt3,
    const float* w0, const float* w1, const float* w2, const float* w3,
    const float* wout,
    bf16* wbt1, bf16* wbt2, bf16* wbt3,
    bf16* wb0, bf16* wb1, bf16* wb2, bf16* wb3, bf16* wc)
{
    int b = blockIdx.x;
    if (b < 216) { rep_wb(wt1, wbt1, 24, 48, 2, 2, b); return; } b -= 216;
    if (b < 216) { rep_wb(wt2, wbt2, 32, 64, 2, 2, b); return; } b -= 216;
    if (b < 216) { rep_wb(wt3, wbt3, 32, 64, 2, 2, b); return; } b -= 216;
    if (b < 14)  { rep_wbc(w0, wb0, 8,  8,  7,  1, b); return; } b -= 14;
    if (b < 14)  { rep_wbc(w1, wb1, 16, 8,  7,  1, b); return; } b -= 14;
    if (b < 56)  { rep_wbc(w2, wb2, 32, 16, 14, 2, b); return; } b -= 56;
    if (b < 216) { rep_wbc(w3, wb3, 64, 32, 27, 4, b); return; } b -= 216;
    rep_wc16(wout, wc, b);              // 14 blocks
}

// ---------------------------------------------------------------------------
// sumcol: fold column-major partials [col][nrow] -> stats[col]. 1 block/col,
// 256 threads (critical-path latency).
// ---------------------------------------------------------------------------
__global__ __launch_bounds__(TPB) void sumcol_k(
    const float* __restrict__ p, int nrow, float* __restrict__ out)
{
    __shared__ float ws[4];
    const long col = blockIdx.x;
    float s = 0.f;
    for (int r = threadIdx.x; r < nrow; r += TPB) s += p[col * nrow + r];
    float d = 0.f;
    wred2(s, d);
    if ((threadIdx.x & 63) == 0) ws[threadIdx.x >> 6] = s;
    __syncthreads();
    if (threadIdx.x == 0) out[col] = ws[0] + ws[1] + ws[2] + ws[3];
}

// ---------------------------------------------------------------------------
// Unified MFMA direct conv, k=3, pad 1, stride 1 or 2, channels-last.
// BNIN: input is RAW producer output; BN+ReLU applied during staging using
// per-thread sc/sh regs (chunk index thread-fixed; TPB % CHK == 0).
// KK <= 7 (conv0/conv1): K-loop fully unrolled.
// ---------------------------------------------------------------------------
template <int IC, int OCR, int STRIDE, int TZ, int TY, int TX,
          bool INF32, bool CFOUT, bool DOSTATS, bool BNIN>
__global__ __launch_bounds__(TPB) void conv_mfma_k(
    const void* __restrict__ in_, const bf16* __restrict__ wb,
    bf16* __restrict__ out, float* __restrict__ outf,
    int ID, int IH, int IW, int OD, int OH, int OW, int CSin, int CSout,
    float* __restrict__ prt, int nrow,
    const float* __restrict__ bst, const float* __restrict__ bg,
    const float* __restrict__ bb, float binvN)
{
    constexpr int EZ = STRIDE * TZ + 3 - STRIDE;
    constexpr int EY = STRIDE * TY + 3 - STRIDE;
    constexpr int EX = STRIDE * TX + 3 - STRIDE;
    constexpr int NR = EZ * EY * EX;
    constexpr int PITCH = (IC == 8) ? 8 : IC + 8;
    constexpr int CHK = IC / 8;
    constexpr int KK = (27 * IC + 31) / 32;
    constexpr int NT = (OCR + 15) / 16;
    constexpr int MT = (TY * TX) / 16;
    constexpr int MROWS = 16 / TX;
    static_assert(TZ == 4, "wave = z-slice");
    static_assert(TPB % CHK == 0, "thread-fixed chunk");
    __shared__ __align__(16) bf16 si[NR * PITCH];
    __shared__ float ps[4][2 * 16 * NT];
    const int ntx = OW / TX, nty = OH / TY;
    const int bx = blockIdx.x % ntx;
    const int by = (blockIdx.x / ntx) % nty;
    const int bz = blockIdx.x / (ntx * nty);
    const int x0 = bx * TX * STRIDE - 1;
    const int y0 = by * TY * STRIDE - 1;
    const int z0 = bz * TZ * STRIDE - 1;

    if constexpr (INF32) {
        static_assert(!INF32 || (IC == 8 && PITCH == 8), "INF32 assumes IC=8");
        const float* x = (const float*)in_;
        const long S = (long)ID * IH * IW;
        for (int i = threadIdx.x; i < NR; i += TPB) {
            int rx = i % EX; int t = i / EX; int ry = t % EY; int rz = t / EY;
            int gz = z0 + rz, gy = y0 + ry, gx = x0 + rx;
            bf16 o[8];
            if ((unsigned)gz < (unsigned)ID && (unsigned)gy < (unsigned)IH &&
                (unsigned)gx < (unsigned)IW) {
                const float* p = x + ((long)gz * IH + gy) * IW + gx;
#pragma unroll
                for (int c = 0; c < 8; ++c)
                    o[c] = __float2bfloat16(p[(long)c * S]);
            } else {
#pragma unroll
                for (int c = 0; c < 8; ++c) o[c] = __float2bfloat16(0.f);
            }
            *(uint4*)(si + i * 8) = *(const uint4*)o;
        }
    } else {
        const bf16* in = (const bf16*)in_;
        float sc[8], sh[8];
        if constexpr (BNIN)
            bnco(bst, bg, bb, binvN, (threadIdx.x % CHK) * 8, sc, sh);
        for (int i = threadIdx.x; i < NR * CHK; i += TPB) {
            int r = i / CHK, c = i % CHK;
            int rx = r % EX, ry = (r / EX) % EY, rz = r / (EX * EY);
            int gz = z0 + rz, gy = y0 + ry, gx = x0 + rx;
            bool ok = (unsigned)gz < (unsigned)ID && (unsigned)gy < (unsigned)IH &&
                      (unsigned)gx < (unsigned)IW;
            uint4 u = make_uint4(0u, 0u, 0u, 0u);
            if (ok)
                u = *(const uint4*)(in + (((long)gz * IH + gy) * IW + gx) * CSin + c * 8);
            if constexpr (BNIN) {
                bf16 o[8];
                if (ok) bnap(u, sc, sh, o);
                else {
#pragma unroll
                    for (int j = 0; j < 8; ++j) o[j] = __float2bfloat16(0.f);
                }
                *(uint4*)(si + r * PITCH + c * 8) = *(const uint4*)o;
            } else {
                *(uint4*)(si + r * PITCH + c * 8) = u;
            }
        }
    }
    __syncthreads();

    const int w = threadIdx.x >> 6;     // z-slice within tile
    const int lane = threadIdx.x & 63;
    const int q = lane >> 4, m = lane & 15;
    const int vy = m / TX, vx = m % TX;

    f4v acc[MT][NT];
#pragma unroll
    for (int mt = 0; mt < MT; ++mt)
#pragma unroll
        for (int nt = 0; nt < NT; ++nt) acc[mt][nt] = (f4v)(0.f);

#define KBODY                                                                  \
    {                                                                          \
        int flat = kk * 32 + q * 8;                                            \
        int tb = flat / IC; if (tb > 26) tb = 26;                              \
        const int cb = flat % IC;                                              \
        const int kz = tb / 9, ky = (tb / 3) % 3, kx = tb % 3;                 \
        s8v bfr[NT];                                                           \
        _Pragma("unroll")                                                      \
        for (int nt = 0; nt < NT; ++nt)                                        \
            bfr[nt] = *(const s8v*)(wb + ((long)(kk * NT + nt) << 9) + lane * 8); \
        const int iz = w * STRIDE + kz;                                        \
        const int ixc = vx * STRIDE + kx;                                      \
        _Pragma("unroll")                                                      \
        for (int mt = 0; mt < MT; ++mt) {                                      \
            int iy = (mt * MROWS + vy) * STRIDE + ky;                          \
            int row = (iz * EY + iy) * EX + ixc;                               \
            s8v av = *(const s8v*)(si + row * PITCH + cb);                     \
            _Pragma("unroll")                                                  \
            for (int nt = 0; nt < NT; ++nt)                                    \
                acc[mt][nt] = __builtin_amdgcn_mfma_f32_16x16x32_bf16(         \
                    av, bfr[nt], acc[mt][nt], 0, 0, 0);                        \
        }                                                                      \
    }

    if constexpr (KK <= 7) {
#pragma unroll
        for (int kk = 0; kk < KK; ++kk) KBODY
    } else {
#pragma unroll 1
        for (int kk = 0; kk < KK; ++kk) KBODY
    }
#undef KBODY

    // epilogue: store + stats (stats are over the RAW output)
    float ls[NT], ls2[NT];
#pragma unroll
    for (int nt = 0; nt < NT; ++nt) { ls[nt] = 0.f; ls2[nt] = 0.f; }
    const int oz = bz * TZ + w;
#pragma unroll
    for (int mt = 0; mt < MT; ++mt)
#pragma unroll
        for (int nt = 0; nt < NT; ++nt) {
            const int n_ch = nt * 16 + m;
            if constexpr (DOSTATS) {
#pragma unroll
                for (int r = 0; r < 4; ++r) {
                    float v = acc[mt][nt][r];
                    ls[nt] += v; ls2[nt] += v * v;   // padded cols are exactly 0
                }
            }
            if (n_ch < OCR) {
#pragma unroll
                for (int r = 0; r < 4; ++r) {
                    int vrow = 4 * q + r;
                    int oy = by * TY + mt * MROWS + vrow / TX;
                    int ox = bx * TX + vrow % TX;
                    long vox = ((long)oz * OH + oy) * OW + ox;
                    if constexpr (CFOUT) {
                        long Sout = (long)OD * OH * OW;
                        outf[(long)n_ch * Sout + vox] = acc[mt][nt][r];
                    } else {
                        out[vox * CSout + n_ch] = __float2bfloat16(acc[mt][nt][r]);
                    }
                }
            }
        }
    if constexpr (DOSTATS) {
#pragma unroll
        for (int nt = 0; nt < NT; ++nt) {
            float t = ls[nt], t2 = ls2[nt];
            t  += __shfl_down(t, 32, 64);  t  += __shfl_down(t, 16, 64);
            t2 += __shfl_down(t2, 32, 64); t2 += __shfl_down(t2, 16, 64);
            if (lane < 16) {
                ps[w][2 * (nt * 16 + lane)]     = t;
                ps[w][2 * (nt * 16 + lane) + 1] = t2;
            }
        }
        __syncthreads();
        if (threadIdx.x < 2 * OCR) {
            float v = ps[0][threadIdx.x] + ps[1][threadIdx.x]
                    + ps[2][threadIdx.x] + ps[3][threadIdx.x];
            prt[(long)threadIdx.x * nrow + blockIdx.x] = v;
        }
    }
}

// ---------------------------------------------------------------------------
// Specialized final conv v5: two-phase K=16 split. LDS holds 16 of the 32
// input channels at a time (si[600][16] = 19.2KB, was 38.4) -> up to 8
// blocks/CU (was exactly 4; r11 counters: LDS pipe ~51% busy, latency-bound).
// Phase h stages channels h*16..h*16+15 (BN fused; chunk boundaries align
// with the cat(0-23)/s1(24-31) split), computes 9 (kz,kx) combos with
// v_mfma_f32_16x16x16_bf16 (b64 A-fragments), accumulating across phases.
// Same LDS bytes and FLOPs as v4 -- the win is pure occupancy.
// ---------------------------------------------------------------------------
__global__ __launch_bounds__(TPB, 6) void outconv_k(
    const bf16* __restrict__ cat, const bf16* __restrict__ s1v,
    const bf16* __restrict__ wc, float* __restrict__ outf,
    const float* __restrict__ stats, const float* __restrict__ g,
    const float* __restrict__ b,
    const float* __restrict__ stS, const float* __restrict__ gS,
    const float* __restrict__ bS, float invN)
{
    constexpr int EY = 10, EX = 10, PITCH = 16;
    __shared__ __align__(16) bf16 si[600 * PITCH];
    const int bx = blockIdx.x & 15;
    const int by = (blockIdx.x >> 4) & 15;
    const int bz = blockIdx.x >> 8;
    const int x0 = bx * 8 - 1, y0 = by * 8 - 1, z0 = bz * 4 - 1;

    const int w = threadIdx.x >> 6;
    const int lane = threadIdx.x & 63;
    const int q = lane >> 4, m = lane & 15;
    const int vy = (m >> 3) & 1, vx = m & 7;

    // staging role: thread -> (column 0..99, 8-ch chunk 0..1); 200 active
    const int scc = threadIdx.x >> 1;
    const int sc2 = threadIdx.x & 1;
    const bool sact = scc < 100;
    const int sry = scc / 10, srx = scc - sry * 10;
    const int sgy = y0 + sry, sgx = x0 + srx;
    const long svyx = (long)sgy * 128 + sgx;
    const bool syx = ((unsigned)sgy < 128u) & ((unsigned)sgx < 128u);
    const bool inter = (bx > 0) & (bx < 15) & (by > 0) & (by < 15) &
                       (bz > 0) & (bz < 31);

    f4v acc[4];
#pragma unroll
    for (int mt = 0; mt < 4; ++mt) acc[mt] = (f4v)(0.f);

#pragma unroll
    for (int h = 0; h < 2; ++h) {
        if (sact) {
            const int ch0 = h * 16 + sc2 * 8;
            float sc[8], sh[8];
            if (ch0 < 24) bnco(stats, g, b, invN, ch0, sc, sh);
            else          bnco(stS, gS, bS, invN, 0, sc, sh);
            const bf16* srcb = (ch0 < 24) ? (cat + ch0) : s1v;
            const long cs = (ch0 < 24) ? 24 : 8;
            uint4 u[6];
            unsigned zm = 0u;
            if (inter) {
#pragma unroll
                for (int rz = 0; rz < 6; ++rz) {
                    long vox = ((long)(z0 + rz) << 14) + svyx;
                    u[rz] = *(const uint4*)(srcb + vox * cs);
                }
                zm = 0x3fu;
            } else {
#pragma unroll
                for (int rz = 0; rz < 6; ++rz) {
                    u[rz] = make_uint4(0u, 0u, 0u, 0u);
                    int gz = z0 + rz;
                    if (syx && (unsigned)gz < 128u) {
                        long vox = ((long)gz << 14) + svyx;
                        u[rz] = *(const uint4*)(srcb + vox * cs);
                        zm |= 1u << rz;
                    }
                }
            }
#pragma unroll
            for (int rz = 0; rz < 6; ++rz) {
                bf16 o[8];
                if ((zm >> rz) & 1u) bnap(u[rz], sc, sh, o);
                else {
#pragma unroll
                    for (int j = 0; j < 8; ++j) o[j] = __float2bfloat16(0.f);
                }
                *(uint4*)(si + (rz * 100 + scc) * PITCH + sc2 * 8) =
                    *(const uint4*)o;
            }
        }
        __syncthreads();

        // compute half h: 81 b64 A-reads, 108 K=16 MFMAs
#pragma unroll
        for (int kz = 0; kz < 3; ++kz) {
#pragma unroll
            for (int kx = 0; kx < 3; ++kx) {
                const bf16* sp = si +
                    ((((w + kz) * EY + vy) * EX) + vx + kx) * PITCH + q * 4;
                s4v a[9];
#pragma unroll
                for (int j = 0; j < 9; ++j)
                    a[j] = *(const s4v*)(sp + j * (EX * PITCH));
                // wc16 index: ((tap*2 + h)*2 + n)*16 + ci; ky step = +192
                const bf16* bp = wc +
                    (((kz * 9 + kx) * 2 + h) * 2 + (m & 1)) * 16 + q * 4;
                s4v bf0 = *(const s4v*)(bp);
                s4v bf1 = *(const s4v*)(bp + 192);
                s4v bf2 = *(const s4v*)(bp + 384);
#pragma unroll
                for (int mt = 0; mt < 4; ++mt) {
                    acc[mt] = __builtin_amdgcn_mfma_f32_16x16x16bf16_1k(
                        a[2 * mt + 0], bf0, acc[mt], 0, 0, 0);
                    acc[mt] = __builtin_amdgcn_mfma_f32_16x16x16bf16_1k(
                        a[2 * mt + 1], bf1, acc[mt], 0, 0, 0);
                    acc[mt] = __builtin_amdgcn_mfma_f32_16x16x16bf16_1k(
                        a[2 * mt + 2], bf2, acc[mt], 0, 0, 0);
                }
            }
        }
        __syncthreads();
    }

    if (m < 2) {
        const long Sout = 128L * 128 * 128;
        const int oz = bz * 4 + w;
#pragma unroll
        for (int mt = 0; mt < 4; ++mt) {
#pragma unroll
            for (int r = 0; r < 4; ++r) {
                int vrow = 4 * q + r;
                int oy = by * 8 + mt * 2 + (vrow >> 3);
                int ox = bx * 8 + (vrow & 7);
                outf[(long)m * Sout + (((long)oz * 128 + oy) * 128 + ox)] =
                    acc[mt][r];
            }
        }
    }
}

// ---------------------------------------------------------------------------
// MFMA transposed conv, stride 2, k=3. BN+ReLU of the (raw) input fused into
// staging (thread-fixed chunk). Channels < C0 use stat group 0, >= C0 group 1.
// PITCH = 64 for IC=48, 72 for IC=64.
// ---------------------------------------------------------------------------
template <int IC, int OCR>
__global__ __launch_bounds__(TPB) void tconv_mfma_k(
    const bf16* __restrict__ in, const bf16* __restrict__ wb,
    bf16* __restrict__ out, int ID, int IH, int IW, int CSin, int CSout,
    float* __restrict__ prt, int nrow,
    const float* __restrict__ st0, const float* __restrict__ g0p,
    const float* __restrict__ b0p, const float* __restrict__ st1,
    const float* __restrict__ g1p, const float* __restrict__ b1p,
    float binvN, int C0)
{
    constexpr int KC = (IC + 31) / 32;
    constexpr int NT = (OCR + 15) / 16;
    constexpr int TZ = 4, TY = 4, TX = 8;
    constexpr int EZ = TZ + 1, EY = TY + 1, EX = TX + 1;
    constexpr int NR = EZ * EY * EX;
    constexpr int PITCH = (IC == 48) ? 64 : 72;
    constexpr int CHKS = 8;
    constexpr int CHK = IC / 8;
    __shared__ __align__(16) bf16 si[NR * PITCH];
    __shared__ float ps[4][64];
    const int ntx = IW / TX, nty = IH / TY;
    const int bx = blockIdx.x % ntx;
    const int by = (blockIdx.x / ntx) % nty;
    const int bz = blockIdx.x / (ntx * nty);
    const int x0 = bx * TX, y0 = by * TY, z0 = bz * TZ;

    // per-thread BN coeffs for fixed chunk c = tid & 7
    {
        const int c = threadIdx.x & 7;
        float sc[8], sh[8];
#pragma unroll
        for (int j = 0; j < 8; ++j) { sc[j] = 1.f; sh[j] = 0.f; }
        if (c < CHK) {
#pragma unroll
            for (int j = 0; j < 8; ++j) {
                int ch = c * 8 + j;
                const float* st; const float* gg; const float* bbq; int k;
                if (ch < C0) { st = st0; gg = g0p; bbq = b0p; k = ch; }
                else         { st = st1; gg = g1p; bbq = b1p; k = ch - C0; }
                float mean = st[2 * k] * binvN;
                float var  = st[2 * k + 1] * binvN - mean * mean;
                sc[j] = rsqrtf(var + 1e-5f) * gg[k];
                sh[j] = bbq[k] - mean * sc[j];
            }
        }
        for (int i = threadIdx.x; i < NR * CHKS; i += TPB) {
            int r = i >> 3, cc = i & 7;
            int rx = r % EX, ry = (r / EX) % EY, rz = r / (EX * EY);
            int gz = z0 + rz, gy = y0 + ry, gx = x0 + rx;
            bool ok = (cc < CHK) && gz < ID && gy < IH && gx < IW;
            uint4 u = make_uint4(0u, 0u, 0u, 0u);
            if (ok)
                u = *(const uint4*)(in + (((long)gz * IH + gy) * IW + gx) * CSin + cc * 8);
            bf16 o[8];
            if (ok) bnap(u, sc, sh, o);
            else {
#pragma unroll
                for (int j = 0; j < 8; ++j) o[j] = __float2bfloat16(0.f);
            }
            *(uint4*)(si + r * PITCH + cc * 8) = *(const uint4*)o;
        }
    }
    __syncthreads();
    const int w = threadIdx.x >> 6;
    const int lane = threadIdx.x & 63;
    const int q = lane >> 4, m = lane & 15;
    const int vy = m >> 3, vx = m & 7;
    const int OH = 2 * IH, OW = 2 * IW;
    float ls[NT], ls2[NT];
#pragma unroll
    for (int nt = 0; nt < NT; ++nt) { ls[nt] = 0.f; ls2[nt] = 0.f; }

#pragma unroll 1
    for (int cls = 0; cls < 8; ++cls) {
        const int pz = (cls >> 2) & 1, py = (cls >> 1) & 1, px = cls & 1;
        const int ny = 1 + py, nx = 1 + px;
        const int ntap = (1 + pz) * ny * nx;
        f4v acc[2][NT];
#pragma unroll
        for (int mt = 0; mt < 2; ++mt)
#pragma unroll
            for (int nt = 0; nt < NT; ++nt) acc[mt][nt] = (f4v)(0.f);
#pragma unroll 1
        for (int s = 0; s < ntap; ++s) {
            int a = s / (ny * nx), b = (s / nx) % ny, cc = s % nx;
            int dz = pz ? a : 0, dy = py ? b : 0, dx = px ? cc : 0;
            int kz = pz ? (a ? 2 : 0) : 1;
            int ky = py ? (b ? 2 : 0) : 1;
            int kx = px ? (cc ? 2 : 0) : 1;
            int kt = kz * 9 + ky * 3 + kx;
#pragma unroll
            for (int kc = 0; kc < KC; ++kc) {
                const bf16* bp = wb + (long)((kt * KC + kc) * NT) * 512 + lane * 8;
                s8v b0 = *(const s8v*)bp;
                s8v b1 = *(const s8v*)(bp + 512);
#pragma unroll
                for (int mt = 0; mt < 2; ++mt) {
                    int row = ((w + dz) * EY + (2 * mt + vy + dy)) * EX + (vx + dx);
                    s8v av = *(const s8v*)(si + row * PITCH + kc * 32 + q * 8);
                    acc[mt][0] = __builtin_amdgcn_mfma_f32_16x16x32_bf16(
                        av, b0, acc[mt][0], 0, 0, 0);
                    acc[mt][1] = __builtin_amdgcn_mfma_f32_16x16x32_bf16(
                        av, b1, acc[mt][1], 0, 0, 0);
                }
            }
        }
        const int z = 2 * (z0 + w) + pz;
#pragma unroll
        for (int mt = 0; mt < 2; ++mt)
#pragma unroll
            for (int nt = 0; nt < NT; ++nt) {
                const int n_ch = nt * 16 + m;
#pragma unroll
                for (int r = 0; r < 4; ++r) {
                    float v = acc[mt][nt][r];
                    ls[nt] += v; ls2[nt] += v * v;
                }
                if (n_ch < OCR) {
#pragma unroll
                    for (int r = 0; r < 4; ++r) {
                        int vrow = 4 * q + r;
                        int yy = 2 * (y0 + 2 * mt + (vrow >> 3)) + py;
                        int xx = 2 * (x0 + (vrow & 7)) + px;
                        out[(((long)z * OH + yy) * OW + xx) * CSout + n_ch] =
                            __float2bfloat16(acc[mt][nt][r]);
                    }
                }
            }
    }
#pragma unroll
    for (int nt = 0; nt < NT; ++nt) {
        float t = ls[nt], t2 = ls2[nt];
        t  += __shfl_down(t, 32, 64);  t  += __shfl_down(t, 16, 64);
        t2 += __shfl_down(t2, 32, 64); t2 += __shfl_down(t2, 16, 64);
        if (lane < 16) {
            ps[w][2 * (nt * 16 + lane)]     = t;
            ps[w][2 * (nt * 16 + lane) + 1] = t2;
        }
    }
    __syncthreads();
    if (threadIdx.x < 2 * OCR) {
        float v = ps[0][threadIdx.x] + ps[1][threadIdx.x] + ps[2][threadIdx.x]
                + ps[3][threadIdx.x];
        prt[(long)threadIdx.x * nrow + blockIdx.x] = v;
    }
}

extern "C" void kernel_launch(void* const* d_in, const int* in_sizes, int n_in,
                              void* d_out, int out_size, void* d_ws, size_t ws_size,
                              hipStream_t stream)
{
    const float* x    = (const float*)d_in[0];
    const float* w0   = (const float*)d_in[1];
    const float* g0   = (const float*)d_in[2];
    const float* b0   = (const float*)d_in[3];
    const float* w1   = (const float*)d_in[4];
    const float* g1   = (const float*)d_in[5];
    const float* b1   = (const float*)d_in[6];
    const float* w2   = (const float*)d_in[7];
    const float* g2   = (const float*)d_in[8];
    const float* b2   = (const float*)d_in[9];
    const float* w3   = (const float*)d_in[10];
    const float* g3   = (const float*)d_in[11];
    const float* b3   = (const float*)d_in[12];
    const float* wt3  = (const float*)d_in[13];
    const float* gt3  = (const float*)d_in[14];
    const float* bt3  = (const float*)d_in[15];
    const float* wt2  = (const float*)d_in[16];
    const float* gt2  = (const float*)d_in[17];
    const float* bt2  = (const float*)d_in[18];
    const float* wt1  = (const float*)d_in[19];
    const float* gt1  = (const float*)d_in[20];
    const float* bt1  = (const float*)d_in[21];
    const float* wout = (const float*)d_in[22];

    const long S128 = 128L * 128 * 128;
    const long S64  = 64L * 64 * 64;
    const long S32  = 32L * 32 * 32;
    const long S16  = 16L * 16 * 16;

    // ---- d_ws: stats | wc16 | activations (ALL raw; BN fused into consumers)
    float* stats = (float*)d_ws;                       // 512 floats
    bf16*  wc    = (bf16*)((char*)d_ws + 2048);        // 3456 bf16 (slot 27648 B)
    bf16* base = (bf16*)((char*)d_ws + 2048 + 27648);
    bf16* cat1 = base;                 // [128^3][24]: tconv1 out (raw)
    bf16* cat2 = cat1 + S128 * 24;     // [64^3][48] : ch0-31 tconv2 raw, ch32-47 s2 raw
    bf16* cat3 = cat2 + S64 * 48;      // [32^3][64] : ch0-31 tconv3 raw, ch32-63 s4 raw
    bf16* s8   = cat3 + S32 * 64;      // [16^3][64] raw
    bf16* s1   = s8 + S16 * 64;        // [128^3][8] raw
    bf16* s2 = cat2 + 32;
    bf16* s4 = cat3 + 32;

    // ---- d_out scratch (all consumed before the final out-conv writes) ----
    bf16*  wbb  = (bf16*)d_out;
    bf16*  wbt1 = wbb;                  // 55296
    bf16*  wbt2 = wbb + 55296;          // 55296
    bf16*  wbt3 = wbb + 110592;         // 55296
    bf16*  wb0  = wbb + 165888;         // 3584
    bf16*  wb1  = wbb + 169472;         // 3584
    bf16*  wb2  = wbb + 173056;         // 14336
    bf16*  wb3  = wbb + 187392;         // 55296 (ends 242688 = 485 KB)
    float* prt  = (float*)d_out + 524288;  // partials, col-major (2 MB offset)

    // One init dispatch: all weight repacks (962 blocks).
    init_all_k<<<962, TPB, 0, stream>>>(
        wt1, wt2, wt3, w0, w1, w2, w3, wout,
        wbt1, wbt2, wbt3, wb0, wb1, wb2, wb3, wc);

    // ---- encoder (all outputs raw; stats via prt+sumcol; no bnrelu passes)
    // conv0: fp32 CF [8][128^3] -> s1 raw. 8192 blocks.
    conv_mfma_k<8, 8, 1, 4, 8, 8, true, false, true, false><<<8192, TPB, 0, stream>>>(
        x, wb0, s1, nullptr, 128, 128, 128, 128, 128, 128, 0, 8, prt, 8192,
        nullptr, nullptr, nullptr, 0.f);
    sumcol_k<<<16, TPB, 0, stream>>>(prt, 8192, stats + 0);

    // conv1: s1 raw (BN g0/b0 in staging) -> s2 raw. 1024 blocks.
    conv_mfma_k<8, 16, 2, 4, 8, 8, false, false, true, true><<<1024, TPB, 0, stream>>>(
        s1, wb1, s2, nullptr, 128, 128, 128, 64, 64, 64, 8, 48, prt, 1024,
        stats + 0, g0, b0, 1.f / S128);
    sumcol_k<<<32, TPB, 0, stream>>>(prt, 1024, stats + 16);

    // conv2: s2 raw (BN g1/b1) -> s4 raw. 512 blocks.
    conv_mfma_k<16, 32, 2, 4, 4, 4, false, false, true, true><<<512, TPB, 0, stream>>>(
        s2, wb2, s4, nullptr, 64, 64, 64, 32, 32, 32, 48, 64, prt, 512,
        stats + 16, g1, b1, 1.f / S64);
    sumcol_k<<<64, TPB, 0, stream>>>(prt, 512, stats + 48);

    // conv3: s4 raw (BN g2/b2) -> s8 raw. 64 blocks.
    conv_mfma_k<32, 64, 2, 4, 4, 4, false, false, true, true><<<64, TPB, 0, stream>>>(
        s4, wb3, s8, nullptr, 32, 32, 32, 16, 16, 16, 64, 64, prt, 64,
        stats + 48, g2, b2, 1.f / S32);
    sumcol_k<<<128, TPB, 0, stream>>>(prt, 64, stats + 112);

    // ---- decoder ----
    // tconv3: s8 raw (BN g3/b3, all 64ch) -> cat3 ch0-31 raw. 32 blocks.
    tconv_mfma_k<64, 32><<<32, TPB, 0, stream>>>(
        s8, wbt3, cat3, 16, 16, 16, 64, 64, prt, 32,
        stats + 112, g3, b3, stats + 112, g3, b3, 1.f / S16, 64);
    sumcol_k<<<64, TPB, 0, stream>>>(prt, 32, stats + 240);

    // tconv2: cat3 (ch0-31 BN gt3/bt3, ch32-63 BN g2/b2) -> cat2 ch0-31 raw.
    tconv_mfma_k<64, 32><<<256, TPB, 0, stream>>>(
        cat3, wbt2, cat2, 32, 32, 32, 64, 48, prt, 256,
        stats + 240, gt3, bt3, stats + 48, g2, b2, 1.f / S32, 32);
    sumcol_k<<<64, TPB, 0, stream>>>(prt, 256, stats + 304);

    // tconv1: cat2 (ch0-31 BN gt2/bt2, ch32-47 BN g1/b1) -> cat1 raw. 2048 blocks.
    tconv_mfma_k<48, 24><<<2048, TPB, 0, stream>>>(
        cat2, wbt1, cat1, 64, 64, 64, 48, 24, prt, 2048,
        stats + 304, gt2, gt2 ? bt2 : bt2, stats + 16, g1, b1, 1.f / S64, 32);
    sumcol_k<<<48, TPB, 0, stream>>>(prt, 2048, stats + 368);

    // out conv: cat1 raw (BN gt1/bt1) + s1 raw (BN g0/b0) -> d_out fp32 [2][128^3].
    outconv_k<<<8192, TPB, 0, stream>>>(
        cat1, s1, wc, (float*)d_out, stats + 368, gt1, bt1,
        stats + 0, g0, b0, 1.f / S128);
}

// Round 13
// 498.140 us; speedup vs baseline: 1.2324x; 1.2324x over previous
//
#include <hip/hip_runtime.h>
#include <hip/hip_bf16.h>

typedef __hip_bfloat16 bf16;
#define TPB 256

typedef __attribute__((ext_vector_type(8))) short s8v;
typedef __attribute__((ext_vector_type(4))) float f4v;

__device__ inline void wred2(float& a, float& b) {
#pragma unroll
    for (int o = 32; o > 0; o >>= 1) {
        a += __shfl_down(a, o, 64);
        b += __shfl_down(b, o, 64);
    }
}

// BN coeff setup: sc/sh for 8 channels starting at ch0 within a stats region.
__device__ inline void bnco(const float* st, const float* g, const float* b,
                            float invN, int ch0, float* sc, float* sh) {
#pragma unroll
    for (int j = 0; j < 8; ++j) {
        int ch = ch0 + j;
        float mean = st[2 * ch] * invN;
        float var  = st[2 * ch + 1] * invN - mean * mean;
        sc[j] = rsqrtf(var + 1e-5f) * g[ch];
        sh[j] = b[ch] - mean * sc[j];
    }
}
// apply BN+ReLU to a 16B bf16x8 chunk (u) -> packed o
__device__ inline void bnap(const uint4& u, const float* sc, const float* sh,
                            bf16* o) {
    const unsigned short* s = (const unsigned short*)&u;
#pragma unroll
    for (int j = 0; j < 8; ++j) {
        float v = __uint_as_float((unsigned)s[j] << 16);
        v = v * sc[j] + sh[j];
        o[j] = __float2bfloat16(v > 0.f ? v : 0.f);
    }
}

// ---------------------------------------------------------------------------
// Repack bodies as device functions (virtual block index vb), merged into a
// single init_all_k dispatch. Stats stay in the prt+sumcol path (round-10
// A/B: same-address atomicAdd stats throttled conv0 ~2x). Round-12 A/B:
// outconv K=16 split spilled (WRITE 316MB = scratch fingerprint) -- keep the
// K=32 / PITCH=32 / 4-blocks-per-CU version (52 VGPR, no spill).
// ---------------------------------------------------------------------------
__device__ inline void rep_wbc(const float* __restrict__ w,
                               bf16* __restrict__ wb,
                               int OCR, int IC, int KK, int NT, int vb)
{
    int idx = vb * TPB + (int)threadIdx.x;
    int tot = KK * NT * 512;
    if (idx >= tot) return;
    int j = idx & 7;
    int l = (idx >> 3) & 63;
    int rest = idx >> 9;
    int nt = rest % NT;
    int kk = rest / NT;
    int n = nt * 16 + (l & 15);
    int k = kk * 32 + (l >> 4) * 8 + j;
    int tap = k / IC, ci = k % IC;
    float v = (n < OCR && tap < 27) ? w[(n * IC + ci) * 27 + tap] : 0.f;
    wb[idx] = __float2bfloat16(v);
}

__device__ inline void rep_wb(const float* __restrict__ w,
                              bf16* __restrict__ wb,
                              int OCR, int IC, int KC, int NT, int vb)
{
    int idx = vb * TPB + (int)threadIdx.x;
    int tot = 27 * KC * NT * 512;
    if (idx >= tot) return;
    int j = idx & 7;
    int l = (idx >> 3) & 63;
    int rest = idx >> 9;
    int nt = rest % NT;
    int kc = (rest / NT) % KC;
    int kt = rest / (NT * KC);
    int n = nt * 16 + (l & 15);
    int k = kc * 32 + (l >> 4) * 8 + j;
    float v = (n < OCR && k < IC) ? w[(n * IC + k) * 27 + kt] : 0.f;
    wb[idx] = __float2bfloat16(v);
}

// Final-conv compact weights: wc[tap 27][n 2][ci 32] bf16 (3456 B).
__device__ inline void rep_wc(const float* __restrict__ w,
                              bf16* __restrict__ wc, int vb)
{
    int idx = vb * TPB + (int)threadIdx.x;
    if (idx >= 1728) return;
    int ci = idx & 31;
    int n = (idx >> 5) & 1;
    int tap = idx >> 6;
    wc[idx] = __float2bfloat16(w[(n * 32 + ci) * 27 + tap]);
}

__global__ __launch_bounds__(TPB) void init_all_k(
    const float* wt1, const float* wt2, const float* wt3,
    const float* w0, const float* w1, const float* w2, const float* w3,
    const float* wout,
    bf16* wbt1, bf16* wbt2, bf16* wbt3,
    bf16* wb0, bf16* wb1, bf16* wb2, bf16* wb3, bf16* wc)
{
    int b = blockIdx.x;
    if (b < 216) { rep_wb(wt1, wbt1, 24, 48, 2, 2, b); return; } b -= 216;
    if (b < 216) { rep_wb(wt2, wbt2, 32, 64, 2, 2, b); return; } b -= 216;
    if (b < 216) { rep_wb(wt3, wbt3, 32, 64, 2, 2, b); return; } b -= 216;
    if (b < 14)  { rep_wbc(w0, wb0, 8,  8,  7,  1, b); return; } b -= 14;
    if (b < 14)  { rep_wbc(w1, wb1, 16, 8,  7,  1, b); return; } b -= 14;
    if (b < 56)  { rep_wbc(w2, wb2, 32, 16, 14, 2, b); return; } b -= 56;
    if (b < 216) { rep_wbc(w3, wb3, 64, 32, 27, 4, b); return; } b -= 216;
    rep_wc(wout, wc, b);                // 7 blocks
}

// ---------------------------------------------------------------------------
// sumcol: fold column-major partials [col][nrow] -> stats[col]. 1 block/col,
// 256 threads (critical-path latency).
// ---------------------------------------------------------------------------
__global__ __launch_bounds__(TPB) void sumcol_k(
    const float* __restrict__ p, int nrow, float* __restrict__ out)
{
    __shared__ float ws[4];
    const long col = blockIdx.x;
    float s = 0.f;
    for (int r = threadIdx.x; r < nrow; r += TPB) s += p[col * nrow + r];
    float d = 0.f;
    wred2(s, d);
    if ((threadIdx.x & 63) == 0) ws[threadIdx.x >> 6] = s;
    __syncthreads();
    if (threadIdx.x == 0) out[col] = ws[0] + ws[1] + ws[2] + ws[3];
}

// ---------------------------------------------------------------------------
// Unified MFMA direct conv, k=3, pad 1, stride 1 or 2, channels-last.
// BNIN: input is RAW producer output; BN+ReLU applied during staging using
// per-thread sc/sh regs (chunk index thread-fixed; TPB % CHK == 0).
// KK <= 7 (conv0/conv1): K-loop fully unrolled.
// ---------------------------------------------------------------------------
template <int IC, int OCR, int STRIDE, int TZ, int TY, int TX,
          bool INF32, bool CFOUT, bool DOSTATS, bool BNIN>
__global__ __launch_bounds__(TPB) void conv_mfma_k(
    const void* __restrict__ in_, const bf16* __restrict__ wb,
    bf16* __restrict__ out, float* __restrict__ outf,
    int ID, int IH, int IW, int OD, int OH, int OW, int CSin, int CSout,
    float* __restrict__ prt, int nrow,
    const float* __restrict__ bst, const float* __restrict__ bg,
    const float* __restrict__ bb, float binvN)
{
    constexpr int EZ = STRIDE * TZ + 3 - STRIDE;
    constexpr int EY = STRIDE * TY + 3 - STRIDE;
    constexpr int EX = STRIDE * TX + 3 - STRIDE;
    constexpr int NR = EZ * EY * EX;
    constexpr int PITCH = (IC == 8) ? 8 : IC + 8;
    constexpr int CHK = IC / 8;
    constexpr int KK = (27 * IC + 31) / 32;
    constexpr int NT = (OCR + 15) / 16;
    constexpr int MT = (TY * TX) / 16;
    constexpr int MROWS = 16 / TX;
    static_assert(TZ == 4, "wave = z-slice");
    static_assert(TPB % CHK == 0, "thread-fixed chunk");
    __shared__ __align__(16) bf16 si[NR * PITCH];
    __shared__ float ps[4][2 * 16 * NT];
    const int ntx = OW / TX, nty = OH / TY;
    const int bx = blockIdx.x % ntx;
    const int by = (blockIdx.x / ntx) % nty;
    const int bz = blockIdx.x / (ntx * nty);
    const int x0 = bx * TX * STRIDE - 1;
    const int y0 = by * TY * STRIDE - 1;
    const int z0 = bz * TZ * STRIDE - 1;

    if constexpr (INF32) {
        static_assert(!INF32 || (IC == 8 && PITCH == 8), "INF32 assumes IC=8");
        const float* x = (const float*)in_;
        const long S = (long)ID * IH * IW;
        for (int i = threadIdx.x; i < NR; i += TPB) {
            int rx = i % EX; int t = i / EX; int ry = t % EY; int rz = t / EY;
            int gz = z0 + rz, gy = y0 + ry, gx = x0 + rx;
            bf16 o[8];
            if ((unsigned)gz < (unsigned)ID && (unsigned)gy < (unsigned)IH &&
                (unsigned)gx < (unsigned)IW) {
                const float* p = x + ((long)gz * IH + gy) * IW + gx;
#pragma unroll
                for (int c = 0; c < 8; ++c)
                    o[c] = __float2bfloat16(p[(long)c * S]);
            } else {
#pragma unroll
                for (int c = 0; c < 8; ++c) o[c] = __float2bfloat16(0.f);
            }
            *(uint4*)(si + i * 8) = *(const uint4*)o;
        }
    } else {
        const bf16* in = (const bf16*)in_;
        float sc[8], sh[8];
        if constexpr (BNIN)
            bnco(bst, bg, bb, binvN, (threadIdx.x % CHK) * 8, sc, sh);
        for (int i = threadIdx.x; i < NR * CHK; i += TPB) {
            int r = i / CHK, c = i % CHK;
            int rx = r % EX, ry = (r / EX) % EY, rz = r / (EX * EY);
            int gz = z0 + rz, gy = y0 + ry, gx = x0 + rx;
            bool ok = (unsigned)gz < (unsigned)ID && (unsigned)gy < (unsigned)IH &&
                      (unsigned)gx < (unsigned)IW;
            uint4 u = make_uint4(0u, 0u, 0u, 0u);
            if (ok)
                u = *(const uint4*)(in + (((long)gz * IH + gy) * IW + gx) * CSin + c * 8);
            if constexpr (BNIN) {
                bf16 o[8];
                if (ok) bnap(u, sc, sh, o);
                else {
#pragma unroll
                    for (int j = 0; j < 8; ++j) o[j] = __float2bfloat16(0.f);
                }
                *(uint4*)(si + r * PITCH + c * 8) = *(const uint4*)o;
            } else {
                *(uint4*)(si + r * PITCH + c * 8) = u;
            }
        }
    }
    __syncthreads();

    const int w = threadIdx.x >> 6;     // z-slice within tile
    const int lane = threadIdx.x & 63;
    const int q = lane >> 4, m = lane & 15;
    const int vy = m / TX, vx = m % TX;

    f4v acc[MT][NT];
#pragma unroll
    for (int mt = 0; mt < MT; ++mt)
#pragma unroll
        for (int nt = 0; nt < NT; ++nt) acc[mt][nt] = (f4v)(0.f);

#define KBODY                                                                  \
    {                                                                          \
        int flat = kk * 32 + q * 8;                                            \
        int tb = flat / IC; if (tb > 26) tb = 26;                              \
        const int cb = flat % IC;                                              \
        const int kz = tb / 9, ky = (tb / 3) % 3, kx = tb % 3;                 \
        s8v bfr[NT];                                                           \
        _Pragma("unroll")                                                      \
        for (int nt = 0; nt < NT; ++nt)                                        \
            bfr[nt] = *(const s8v*)(wb + ((long)(kk * NT + nt) << 9) + lane * 8); \
        const int iz = w * STRIDE + kz;                                        \
        const int ixc = vx * STRIDE + kx;                                      \
        _Pragma("unroll")                                                      \
        for (int mt = 0; mt < MT; ++mt) {                                      \
            int iy = (mt * MROWS + vy) * STRIDE + ky;                          \
            int row = (iz * EY + iy) * EX + ixc;                               \
            s8v av = *(const s8v*)(si + row * PITCH + cb);                     \
            _Pragma("unroll")                                                  \
            for (int nt = 0; nt < NT; ++nt)                                    \
                acc[mt][nt] = __builtin_amdgcn_mfma_f32_16x16x32_bf16(         \
                    av, bfr[nt], acc[mt][nt], 0, 0, 0);                        \
        }                                                                      \
    }

    if constexpr (KK <= 7) {
#pragma unroll
        for (int kk = 0; kk < KK; ++kk) KBODY
    } else {
#pragma unroll 1
        for (int kk = 0; kk < KK; ++kk) KBODY
    }
#undef KBODY

    // epilogue: store + stats (stats are over the RAW output)
    float ls[NT], ls2[NT];
#pragma unroll
    for (int nt = 0; nt < NT; ++nt) { ls[nt] = 0.f; ls2[nt] = 0.f; }
    const int oz = bz * TZ + w;
#pragma unroll
    for (int mt = 0; mt < MT; ++mt)
#pragma unroll
        for (int nt = 0; nt < NT; ++nt) {
            const int n_ch = nt * 16 + m;
            if constexpr (DOSTATS) {
#pragma unroll
                for (int r = 0; r < 4; ++r) {
                    float v = acc[mt][nt][r];
                    ls[nt] += v; ls2[nt] += v * v;   // padded cols are exactly 0
                }
            }
            if (n_ch < OCR) {
#pragma unroll
                for (int r = 0; r < 4; ++r) {
                    int vrow = 4 * q + r;
                    int oy = by * TY + mt * MROWS + vrow / TX;
                    int ox = bx * TX + vrow % TX;
                    long vox = ((long)oz * OH + oy) * OW + ox;
                    if constexpr (CFOUT) {
                        long Sout = (long)OD * OH * OW;
                        outf[(long)n_ch * Sout + vox] = acc[mt][nt][r];
                    } else {
                        out[vox * CSout + n_ch] = __float2bfloat16(acc[mt][nt][r]);
                    }
                }
            }
        }
    if constexpr (DOSTATS) {
#pragma unroll
        for (int nt = 0; nt < NT; ++nt) {
            float t = ls[nt], t2 = ls2[nt];
            t  += __shfl_down(t, 32, 64);  t  += __shfl_down(t, 16, 64);
            t2 += __shfl_down(t2, 32, 64); t2 += __shfl_down(t2, 16, 64);
            if (lane < 16) {
                ps[w][2 * (nt * 16 + lane)]     = t;
                ps[w][2 * (nt * 16 + lane) + 1] = t2;
            }
        }
        __syncthreads();
        if (threadIdx.x < 2 * OCR) {
            float v = ps[0][threadIdx.x] + ps[1][threadIdx.x]
                    + ps[2][threadIdx.x] + ps[3][threadIdx.x];
            prt[(long)threadIdx.x * nrow + blockIdx.x] = v;
        }
    }
}

// ---------------------------------------------------------------------------
// Specialized final conv (round-11 proven, 106us): cat1 [128^3][24] raw +
// s1 [128^3][8] raw -> d_out fp32 CF [2][128^3]. BN of BOTH inputs fused in
// staging. Tile 4x8x8, PITCH=32 (38.4KB LDS, 4 blocks/CU, 52 VGPR no spill),
// compact B wc[tap][2][32] (n = m&1), kz/kx fully unrolled.
// ---------------------------------------------------------------------------
__global__ __launch_bounds__(TPB, 4) void outconv_k(
    const bf16* __restrict__ cat, const bf16* __restrict__ s1v,
    const bf16* __restrict__ wc, float* __restrict__ outf,
    const float* __restrict__ stats, const float* __restrict__ g,
    const float* __restrict__ b,
    const float* __restrict__ stS, const float* __restrict__ gS,
    const float* __restrict__ bS, float invN)
{
    constexpr int EY = 10, EX = 10, PITCH = 32;
    __shared__ __align__(16) bf16 si[600 * PITCH];
    const int bx = blockIdx.x & 15;
    const int by = (blockIdx.x >> 4) & 15;
    const int bz = blockIdx.x >> 8;
    const int x0 = bx * 8 - 1, y0 = by * 8 - 1, z0 = bz * 4 - 1;

    const int c4 = threadIdx.x & 3;
    float sc[8], sh[8];
    if (c4 < 3) bnco(stats, g, b, invN, c4 * 8, sc, sh);
    else        bnco(stS, gS, bS, invN, 0, sc, sh);

    const int col = threadIdx.x >> 2;   // 0..63
    const bool inter = (bx > 0) & (bx < 15) & (by > 0) & (by < 15) &
                       (bz > 0) & (bz < 31);
#pragma unroll
    for (int cp = 0; cp < 2; ++cp) {
        const int cc = col + cp * 64;
        if (cc < 100) {
            const int ry = cc / 10, rx = cc - ry * 10;
            const int gy = y0 + ry, gx = x0 + rx;
            const long vyx = (long)gy * 128 + gx;
            uint4 u[6];
            if (inter) {
#pragma unroll
                for (int rz = 0; rz < 6; ++rz) {
                    long vox = ((long)(z0 + rz) << 14) + vyx;
                    const bf16* p = (c4 == 3) ? (s1v + vox * 8)
                                              : (cat + vox * 24 + c4 * 8);
                    u[rz] = *(const uint4*)p;
                }
#pragma unroll
                for (int rz = 0; rz < 6; ++rz) {
                    bf16 o[8];
                    bnap(u[rz], sc, sh, o);
                    *(uint4*)(si + (rz * 100 + cc) * PITCH + c4 * 8) =
                        *(const uint4*)o;
                }
            } else {
                const bool yxok = ((unsigned)gy < 128u) & ((unsigned)gx < 128u);
                unsigned zm = 0u;
#pragma unroll
                for (int rz = 0; rz < 6; ++rz) {
                    u[rz] = make_uint4(0u, 0u, 0u, 0u);
                    int gz = z0 + rz;
                    if (yxok && (unsigned)gz < 128u) {
                        long vox = ((long)gz << 14) + vyx;
                        const bf16* p = (c4 == 3) ? (s1v + vox * 8)
                                                  : (cat + vox * 24 + c4 * 8);
                        u[rz] = *(const uint4*)p;
                        zm |= 1u << rz;
                    }
                }
#pragma unroll
                for (int rz = 0; rz < 6; ++rz) {
                    bf16 o[8];
                    if ((zm >> rz) & 1u) bnap(u[rz], sc, sh, o);
                    else {
#pragma unroll
                        for (int j = 0; j < 8; ++j) o[j] = __float2bfloat16(0.f);
                    }
                    *(uint4*)(si + (rz * 100 + cc) * PITCH + c4 * 8) =
                        *(const uint4*)o;
                }
            }
        }
    }
    __syncthreads();

    const int w = threadIdx.x >> 6;
    const int lane = threadIdx.x & 63;
    const int q = lane >> 4, m = lane & 15;
    const int vy = (m >> 3) & 1, vx = m & 7;

    f4v acc[4];
#pragma unroll
    for (int mt = 0; mt < 4; ++mt) acc[mt] = (f4v)(0.f);

    const bf16* wcl = wc + (m & 1) * 32 + q * 8;   // + tap*64
#pragma unroll
    for (int kz = 0; kz < 3; ++kz) {
#pragma unroll
        for (int kx = 0; kx < 3; ++kx) {
            const bf16* sp = si +
                ((((w + kz) * EY + vy) * EX) + vx + kx) * PITCH + q * 8;
            s8v a[9];
#pragma unroll
            for (int j = 0; j < 9; ++j)
                a[j] = *(const s8v*)(sp + j * (EX * PITCH));
            const bf16* bp = wcl + (kz * 9 + kx) * 64;
            s8v bf0 = *(const s8v*)(bp);            // ky=0
            s8v bf1 = *(const s8v*)(bp + 3 * 64);   // ky=1
            s8v bf2 = *(const s8v*)(bp + 6 * 64);   // ky=2
#pragma unroll
            for (int mt = 0; mt < 4; ++mt) {
                acc[mt] = __builtin_amdgcn_mfma_f32_16x16x32_bf16(
                    a[2 * mt + 0], bf0, acc[mt], 0, 0, 0);
                acc[mt] = __builtin_amdgcn_mfma_f32_16x16x32_bf16(
                    a[2 * mt + 1], bf1, acc[mt], 0, 0, 0);
                acc[mt] = __builtin_amdgcn_mfma_f32_16x16x32_bf16(
                    a[2 * mt + 2], bf2, acc[mt], 0, 0, 0);
            }
        }
    }
    if (m < 2) {
        const long Sout = 128L * 128 * 128;
        const int oz = bz * 4 + w;
#pragma unroll
        for (int mt = 0; mt < 4; ++mt) {
#pragma unroll
            for (int r = 0; r < 4; ++r) {
                int vrow = 4 * q + r;
                int oy = by * 8 + mt * 2 + (vrow >> 3);
                int ox = bx * 8 + (vrow & 7);
                outf[(long)m * Sout + (((long)oz * 128 + oy) * 128 + ox)] =
                    acc[mt][r];
            }
        }
    }
}

// ---------------------------------------------------------------------------
// MFMA transposed conv, stride 2, k=3. BN+ReLU of the (raw) input fused into
// staging (thread-fixed chunk). Channels < C0 use stat group 0, >= C0 group 1.
// PITCH = 64 for IC=48, 72 for IC=64.
// ---------------------------------------------------------------------------
template <int IC, int OCR>
__global__ __launch_bounds__(TPB) void tconv_mfma_k(
    const bf16* __restrict__ in, const bf16* __restrict__ wb,
    bf16* __restrict__ out, int ID, int IH, int IW, int CSin, int CSout,
    float* __restrict__ prt, int nrow,
    const float* __restrict__ st0, const float* __restrict__ g0p,
    const float* __restrict__ b0p, const float* __restrict__ st1,
    const float* __restrict__ g1p, const float* __restrict__ b1p,
    float binvN, int C0)
{
    constexpr int KC = (IC + 31) / 32;
    constexpr int NT = (OCR + 15) / 16;
    constexpr int TZ = 4, TY = 4, TX = 8;
    constexpr int EZ = TZ + 1, EY = TY + 1, EX = TX + 1;
    constexpr int NR = EZ * EY * EX;
    constexpr int PITCH = (IC == 48) ? 64 : 72;
    constexpr int CHKS = 8;
    constexpr int CHK = IC / 8;
    __shared__ __align__(16) bf16 si[NR * PITCH];
    __shared__ float ps[4][64];
    const int ntx = IW / TX, nty = IH / TY;
    const int bx = blockIdx.x % ntx;
    const int by = (blockIdx.x / ntx) % nty;
    const int bz = blockIdx.x / (ntx * nty);
    const int x0 = bx * TX, y0 = by * TY, z0 = bz * TZ;

    // per-thread BN coeffs for fixed chunk c = tid & 7
    {
        const int c = threadIdx.x & 7;
        float sc[8], sh[8];
#pragma unroll
        for (int j = 0; j < 8; ++j) { sc[j] = 1.f; sh[j] = 0.f; }
        if (c < CHK) {
#pragma unroll
            for (int j = 0; j < 8; ++j) {
                int ch = c * 8 + j;
                const float* st; const float* gg; const float* bbq; int k;
                if (ch < C0) { st = st0; gg = g0p; bbq = b0p; k = ch; }
                else         { st = st1; gg = g1p; bbq = b1p; k = ch - C0; }
                float mean = st[2 * k] * binvN;
                float var  = st[2 * k + 1] * binvN - mean * mean;
                sc[j] = rsqrtf(var + 1e-5f) * gg[k];
                sh[j] = bbq[k] - mean * sc[j];
            }
        }
        for (int i = threadIdx.x; i < NR * CHKS; i += TPB) {
            int r = i >> 3, cc = i & 7;
            int rx = r % EX, ry = (r / EX) % EY, rz = r / (EX * EY);
            int gz = z0 + rz, gy = y0 + ry, gx = x0 + rx;
            bool ok = (cc < CHK) && gz < ID && gy < IH && gx < IW;
            uint4 u = make_uint4(0u, 0u, 0u, 0u);
            if (ok)
                u = *(const uint4*)(in + (((long)gz * IH + gy) * IW + gx) * CSin + cc * 8);
            bf16 o[8];
            if (ok) bnap(u, sc, sh, o);
            else {
#pragma unroll
                for (int j = 0; j < 8; ++j) o[j] = __float2bfloat16(0.f);
            }
            *(uint4*)(si + r * PITCH + cc * 8) = *(const uint4*)o;
        }
    }
    __syncthreads();
    const int w = threadIdx.x >> 6;
    const int lane = threadIdx.x & 63;
    const int q = lane >> 4, m = lane & 15;
    const int vy = m >> 3, vx = m & 7;
    const int OH = 2 * IH, OW = 2 * IW;
    float ls[NT], ls2[NT];
#pragma unroll
    for (int nt = 0; nt < NT; ++nt) { ls[nt] = 0.f; ls2[nt] = 0.f; }

#pragma unroll 1
    for (int cls = 0; cls < 8; ++cls) {
        const int pz = (cls >> 2) & 1, py = (cls >> 1) & 1, px = cls & 1;
        const int ny = 1 + py, nx = 1 + px;
        const int ntap = (1 + pz) * ny * nx;
        f4v acc[2][NT];
#pragma unroll
        for (int mt = 0; mt < 2; ++mt)
#pragma unroll
            for (int nt = 0; nt < NT; ++nt) acc[mt][nt] = (f4v)(0.f);
#pragma unroll 1
        for (int s = 0; s < ntap; ++s) {
            int a = s / (ny * nx), b = (s / nx) % ny, cc = s % nx;
            int dz = pz ? a : 0, dy = py ? b : 0, dx = px ? cc : 0;
            int kz = pz ? (a ? 2 : 0) : 1;
            int ky = py ? (b ? 2 : 0) : 1;
            int kx = px ? (cc ? 2 : 0) : 1;
            int kt = kz * 9 + ky * 3 + kx;
#pragma unroll
            for (int kc = 0; kc < KC; ++kc) {
                const bf16* bp = wb + (long)((kt * KC + kc) * NT) * 512 + lane * 8;
                s8v b0 = *(const s8v*)bp;
                s8v b1 = *(const s8v*)(bp + 512);
#pragma unroll
                for (int mt = 0; mt < 2; ++mt) {
                    int row = ((w + dz) * EY + (2 * mt + vy + dy)) * EX + (vx + dx);
                    s8v av = *(const s8v*)(si + row * PITCH + kc * 32 + q * 8);
                    acc[mt][0] = __builtin_amdgcn_mfma_f32_16x16x32_bf16(
                        av, b0, acc[mt][0], 0, 0, 0);
                    acc[mt][1] = __builtin_amdgcn_mfma_f32_16x16x32_bf16(
                        av, b1, acc[mt][1], 0, 0, 0);
                }
            }
        }
        const int z = 2 * (z0 + w) + pz;
#pragma unroll
        for (int mt = 0; mt < 2; ++mt)
#pragma unroll
            for (int nt = 0; nt < NT; ++nt) {
                const int n_ch = nt * 16 + m;
#pragma unroll
                for (int r = 0; r < 4; ++r) {
                    float v = acc[mt][nt][r];
                    ls[nt] += v; ls2[nt] += v * v;
                }
                if (n_ch < OCR) {
#pragma unroll
                    for (int r = 0; r < 4; ++r) {
                        int vrow = 4 * q + r;
                        int yy = 2 * (y0 + 2 * mt + (vrow >> 3)) + py;
                        int xx = 2 * (x0 + (vrow & 7)) + px;
                        out[(((long)z * OH + yy) * OW + xx) * CSout + n_ch] =
                            __float2bfloat16(acc[mt][nt][r]);
                    }
                }
            }
    }
#pragma unroll
    for (int nt = 0; nt < NT; ++nt) {
        float t = ls[nt], t2 = ls2[nt];
        t  += __shfl_down(t, 32, 64);  t  += __shfl_down(t, 16, 64);
        t2 += __shfl_down(t2, 32, 64); t2 += __shfl_down(t2, 16, 64);
        if (lane < 16) {
            ps[w][2 * (nt * 16 + lane)]     = t;
            ps[w][2 * (nt * 16 + lane) + 1] = t2;
        }
    }
    __syncthreads();
    if (threadIdx.x < 2 * OCR) {
        float v = ps[0][threadIdx.x] + ps[1][threadIdx.x] + ps[2][threadIdx.x]
                + ps[3][threadIdx.x];
        prt[(long)threadIdx.x * nrow + blockIdx.x] = v;
    }
}

extern "C" void kernel_launch(void* const* d_in, const int* in_sizes, int n_in,
                              void* d_out, int out_size, void* d_ws, size_t ws_size,
                              hipStream_t stream)
{
    const float* x    = (const float*)d_in[0];
    const float* w0   = (const float*)d_in[1];
    const float* g0   = (const float*)d_in[2];
    const float* b0   = (const float*)d_in[3];
    const float* w1   = (const float*)d_in[4];
    const float* g1   = (const float*)d_in[5];
    const float* b1   = (const float*)d_in[6];
    const float* w2   = (const float*)d_in[7];
    const float* g2   = (const float*)d_in[8];
    const float* b2   = (const float*)d_in[9];
    const float* w3   = (const float*)d_in[10];
    const float* g3   = (const float*)d_in[11];
    const float* b3   = (const float*)d_in[12];
    const float* wt3  = (const float*)d_in[13];
    const float* gt3  = (const float*)d_in[14];
    const float* bt3  = (const float*)d_in[15];
    const float* wt2  = (const float*)d_in[16];
    const float* gt2  = (const float*)d_in[17];
    const float* bt2  = (const float*)d_in[18];
    const float* wt1  = (const float*)d_in[19];
    const float* gt1  = (const float*)d_in[20];
    const float* bt1  = (const float*)d_in[21];
    const float* wout = (const float*)d_in[22];

    const long S128 = 128L * 128 * 128;
    const long S64  = 64L * 64 * 64;
    const long S32  = 32L * 32 * 32;
    const long S16  = 16L * 16 * 16;

    // ---- d_ws: stats | wc | activations (ALL raw; BN fused into consumers)
    float* stats = (float*)d_ws;                       // 512 floats
    bf16*  wc    = (bf16*)((char*)d_ws + 2048);        // 1728 bf16 (slot 27648 B)
    bf16* base = (bf16*)((char*)d_ws + 2048 + 27648);
    bf16* cat1 = base;                 // [128^3][24]: tconv1 out (raw)
    bf16* cat2 = cat1 + S128 * 24;     // [64^3][48] : ch0-31 tconv2 raw, ch32-47 s2 raw
    bf16* cat3 = cat2 + S64 * 48;      // [32^3][64] : ch0-31 tconv3 raw, ch32-63 s4 raw
    bf16* s8   = cat3 + S32 * 64;      // [16^3][64] raw
    bf16* s1   = s8 + S16 * 64;        // [128^3][8] raw
    bf16* s2 = cat2 + 32;
    bf16* s4 = cat3 + 32;

    // ---- d_out scratch (all consumed before the final out-conv writes) ----
    bf16*  wbb  = (bf16*)d_out;
    bf16*  wbt1 = wbb;                  // 55296
    bf16*  wbt2 = wbb + 55296;          // 55296
    bf16*  wbt3 = wbb + 110592;         // 55296
    bf16*  wb0  = wbb + 165888;         // 3584
    bf16*  wb1  = wbb + 169472;         // 3584
    bf16*  wb2  = wbb + 173056;         // 14336
    bf16*  wb3  = wbb + 187392;         // 55296 (ends 242688 = 485 KB)
    float* prt  = (float*)d_out + 524288;  // partials, col-major (2 MB offset)

    // One init dispatch: all 8 weight repacks (955 blocks).
    init_all_k<<<955, TPB, 0, stream>>>(
        wt1, wt2, wt3, w0, w1, w2, w3, wout,
        wbt1, wbt2, wbt3, wb0, wb1, wb2, wb3, wc);

    // ---- encoder (all outputs raw; stats via prt+sumcol; no bnrelu passes)
    // conv0: fp32 CF [8][128^3] -> s1 raw. 8192 blocks.
    conv_mfma_k<8, 8, 1, 4, 8, 8, true, false, true, false><<<8192, TPB, 0, stream>>>(
        x, wb0, s1, nullptr, 128, 128, 128, 128, 128, 128, 0, 8, prt, 8192,
        nullptr, nullptr, nullptr, 0.f);
    sumcol_k<<<16, TPB, 0, stream>>>(prt, 8192, stats + 0);

    // conv1: s1 raw (BN g0/b0 in staging) -> s2 raw. 1024 blocks.
    conv_mfma_k<8, 16, 2, 4, 8, 8, false, false, true, true><<<1024, TPB, 0, stream>>>(
        s1, wb1, s2, nullptr, 128, 128, 128, 64, 64, 64, 8, 48, prt, 1024,
        stats + 0, g0, b0, 1.f / S128);
    sumcol_k<<<32, TPB, 0, stream>>>(prt, 1024, stats + 16);

    // conv2: s2 raw (BN g1/b1) -> s4 raw. 512 blocks.
    conv_mfma_k<16, 32, 2, 4, 4, 4, false, false, true, true><<<512, TPB, 0, stream>>>(
        s2, wb2, s4, nullptr, 64, 64, 64, 32, 32, 32, 48, 64, prt, 512,
        stats + 16, g1, b1, 1.f / S64);
    sumcol_k<<<64, TPB, 0, stream>>>(prt, 512, stats + 48);

    // conv3: s4 raw (BN g2/b2) -> s8 raw. 64 blocks.
    conv_mfma_k<32, 64, 2, 4, 4, 4, false, false, true, true><<<64, TPB, 0, stream>>>(
        s4, wb3, s8, nullptr, 32, 32, 32, 16, 16, 16, 64, 64, prt, 64,
        stats + 48, g2, b2, 1.f / S32);
    sumcol_k<<<128, TPB, 0, stream>>>(prt, 64, stats + 112);

    // ---- decoder ----
    // tconv3: s8 raw (BN g3/b3, all 64ch) -> cat3 ch0-31 raw. 32 blocks.
    tconv_mfma_k<64, 32><<<32, TPB, 0, stream>>>(
        s8, wbt3, cat3, 16, 16, 16, 64, 64, prt, 32,
        stats + 112, g3, b3, stats + 112, g3, b3, 1.f / S16, 64);
    sumcol_k<<<64, TPB, 0, stream>>>(prt, 32, stats + 240);

    // tconv2: cat3 (ch0-31 BN gt3/bt3, ch32-63 BN g2/b2) -> cat2 ch0-31 raw.
    tconv_mfma_k<64, 32><<<256, TPB, 0, stream>>>(
        cat3, wbt2, cat2, 32, 32, 32, 64, 48, prt, 256,
        stats + 240, gt3, bt3, stats + 48, g2, b2, 1.f / S32, 32);
    sumcol_k<<<64, TPB, 0, stream>>>(prt, 256, stats + 304);

    // tconv1: cat2 (ch0-31 BN gt2/bt2, ch32-47 BN g1/b1) -> cat1 raw. 2048 blocks.
    tconv_mfma_k<48, 24><<<2048, TPB, 0, stream>>>(
        cat2, wbt1, cat1, 64, 64, 64, 48, 24, prt, 2048,
        stats + 304, gt2, bt2, stats + 16, g1, b1, 1.f / S64, 32);
    sumcol_k<<<48, TPB, 0, stream>>>(prt, 2048, stats + 368);

    // out conv: cat1 raw (BN gt1/bt1) + s1 raw (BN g0/b0) -> d_out fp32 [2][128^3].
    outconv_k<<<8192, TPB, 0, stream>>>(
        cat1, s1, wc, (float*)d_out, stats + 368, gt1, bt1,
        stats + 0, g0, b0, 1.f / S128);
}

// Round 14
// 485.683 us; speedup vs baseline: 1.2640x; 1.0256x over previous
//
#include <hip/hip_runtime.h>
#include <hip/hip_bf16.h>

typedef __hip_bfloat16 bf16;
#define TPB 256

typedef __attribute__((ext_vector_type(8))) short s8v;
typedef __attribute__((ext_vector_type(4))) float f4v;

__device__ inline void wred2(float& a, float& b) {
#pragma unroll
    for (int o = 32; o > 0; o >>= 1) {
        a += __shfl_down(a, o, 64);
        b += __shfl_down(b, o, 64);
    }
}

// BN coeff setup: sc/sh for 8 channels starting at ch0 within a stats region.
__device__ inline void bnco(const float* st, const float* g, const float* b,
                            float invN, int ch0, float* sc, float* sh) {
#pragma unroll
    for (int j = 0; j < 8; ++j) {
        int ch = ch0 + j;
        float mean = st[2 * ch] * invN;
        float var  = st[2 * ch + 1] * invN - mean * mean;
        sc[j] = rsqrtf(var + 1e-5f) * g[ch];
        sh[j] = b[ch] - mean * sc[j];
    }
}
// apply BN+ReLU to a 16B bf16x8 chunk (u) -> packed o
__device__ inline void bnap(const uint4& u, const float* sc, const float* sh,
                            bf16* o) {
    const unsigned short* s = (const unsigned short*)&u;
#pragma unroll
    for (int j = 0; j < 8; ++j) {
        float v = __uint_as_float((unsigned)s[j] << 16);
        v = v * sc[j] + sh[j];
        o[j] = __float2bfloat16(v > 0.f ? v : 0.f);
    }
}

// ---------------------------------------------------------------------------
// xpose: x fp32 CF [8][128^3] -> s0 bf16 CL [128^3][8]. Reads coalesced per
// channel plane; writes fully-coalesced 16B rows. ~96MB traffic, HBM-bound.
// Kills conv0's 2.9x CF-gather over-fetch (r10 counters: 186MB for 64MB in).
// ---------------------------------------------------------------------------
__global__ __launch_bounds__(TPB) void xpose_k(
    const float* __restrict__ x, bf16* __restrict__ s0)
{
    const long S = 128L * 128 * 128;
    long v = (long)blockIdx.x * TPB + threadIdx.x;
    bf16 o[8];
#pragma unroll
    for (int c = 0; c < 8; ++c)
        o[c] = __float2bfloat16(x[c * S + v]);
    *(uint4*)(s0 + v * 8) = *(const uint4*)o;
}

// ---------------------------------------------------------------------------
// Repack bodies as device functions (virtual block index vb), merged into a
// single init_all_k dispatch. Stats stay in the prt+sumcol path (round-10
// A/B: same-address atomicAdd stats throttled conv0 ~2x). Round-12 A/B:
// outconv K=16 split spilled (WRITE 316MB = scratch fingerprint) -- keep the
// K=32 / PITCH=32 / 4-blocks-per-CU version (52 VGPR, no spill).
// ---------------------------------------------------------------------------
__device__ inline void rep_wbc(const float* __restrict__ w,
                               bf16* __restrict__ wb,
                               int OCR, int IC, int KK, int NT, int vb)
{
    int idx = vb * TPB + (int)threadIdx.x;
    int tot = KK * NT * 512;
    if (idx >= tot) return;
    int j = idx & 7;
    int l = (idx >> 3) & 63;
    int rest = idx >> 9;
    int nt = rest % NT;
    int kk = rest / NT;
    int n = nt * 16 + (l & 15);
    int k = kk * 32 + (l >> 4) * 8 + j;
    int tap = k / IC, ci = k % IC;
    float v = (n < OCR && tap < 27) ? w[(n * IC + ci) * 27 + tap] : 0.f;
    wb[idx] = __float2bfloat16(v);
}

__device__ inline void rep_wb(const float* __restrict__ w,
                              bf16* __restrict__ wb,
                              int OCR, int IC, int KC, int NT, int vb)
{
    int idx = vb * TPB + (int)threadIdx.x;
    int tot = 27 * KC * NT * 512;
    if (idx >= tot) return;
    int j = idx & 7;
    int l = (idx >> 3) & 63;
    int rest = idx >> 9;
    int nt = rest % NT;
    int kc = (rest / NT) % KC;
    int kt = rest / (NT * KC);
    int n = nt * 16 + (l & 15);
    int k = kc * 32 + (l >> 4) * 8 + j;
    float v = (n < OCR && k < IC) ? w[(n * IC + k) * 27 + kt] : 0.f;
    wb[idx] = __float2bfloat16(v);
}

// Final-conv compact weights: wc[tap 27][n 2][ci 32] bf16 (3456 B).
__device__ inline void rep_wc(const float* __restrict__ w,
                              bf16* __restrict__ wc, int vb)
{
    int idx = vb * TPB + (int)threadIdx.x;
    if (idx >= 1728) return;
    int ci = idx & 31;
    int n = (idx >> 5) & 1;
    int tap = idx >> 6;
    wc[idx] = __float2bfloat16(w[(n * 32 + ci) * 27 + tap]);
}

__global__ __launch_bounds__(TPB) void init_all_k(
    const float* wt1, const float* wt2, const float* wt3,
    const float* w0, const float* w1, const float* w2, const float* w3,
    const float* wout,
    bf16* wbt1, bf16* wbt2, bf16* wbt3,
    bf16* wb0, bf16* wb1, bf16* wb2, bf16* wb3, bf16* wc)
{
    int b = blockIdx.x;
    if (b < 216) { rep_wb(wt1, wbt1, 24, 48, 2, 2, b); return; } b -= 216;
    if (b < 216) { rep_wb(wt2, wbt2, 32, 64, 2, 2, b); return; } b -= 216;
    if (b < 216) { rep_wb(wt3, wbt3, 32, 64, 2, 2, b); return; } b -= 216;
    if (b < 14)  { rep_wbc(w0, wb0, 8,  8,  7,  1, b); return; } b -= 14;
    if (b < 14)  { rep_wbc(w1, wb1, 16, 8,  7,  1, b); return; } b -= 14;
    if (b < 56)  { rep_wbc(w2, wb2, 32, 16, 14, 2, b); return; } b -= 56;
    if (b < 216) { rep_wbc(w3, wb3, 64, 32, 27, 4, b); return; } b -= 216;
    rep_wc(wout, wc, b);                // 7 blocks
}

// ---------------------------------------------------------------------------
// sumcol: fold column-major partials [col][nrow] -> stats[col]. 1 block/col,
// 256 threads (critical-path latency).
// ---------------------------------------------------------------------------
__global__ __launch_bounds__(TPB) void sumcol_k(
    const float* __restrict__ p, int nrow, float* __restrict__ out)
{
    __shared__ float ws[4];
    const long col = blockIdx.x;
    float s = 0.f;
    for (int r = threadIdx.x; r < nrow; r += TPB) s += p[col * nrow + r];
    float d = 0.f;
    wred2(s, d);
    if ((threadIdx.x & 63) == 0) ws[threadIdx.x >> 6] = s;
    __syncthreads();
    if (threadIdx.x == 0) out[col] = ws[0] + ws[1] + ws[2] + ws[3];
}

// ---------------------------------------------------------------------------
// Unified MFMA direct conv, k=3, pad 1, stride 1 or 2, channels-last.
// BNIN: input is RAW producer output; BN+ReLU applied during staging using
// per-thread sc/sh regs (chunk index thread-fixed; TPB % CHK == 0).
// KK <= 7 (conv0/conv1): K-loop fully unrolled.
// ---------------------------------------------------------------------------
template <int IC, int OCR, int STRIDE, int TZ, int TY, int TX,
          bool CFOUT, bool DOSTATS, bool BNIN>
__global__ __launch_bounds__(TPB) void conv_mfma_k(
    const void* __restrict__ in_, const bf16* __restrict__ wb,
    bf16* __restrict__ out, float* __restrict__ outf,
    int ID, int IH, int IW, int OD, int OH, int OW, int CSin, int CSout,
    float* __restrict__ prt, int nrow,
    const float* __restrict__ bst, const float* __restrict__ bg,
    const float* __restrict__ bb, float binvN)
{
    constexpr int EZ = STRIDE * TZ + 3 - STRIDE;
    constexpr int EY = STRIDE * TY + 3 - STRIDE;
    constexpr int EX = STRIDE * TX + 3 - STRIDE;
    constexpr int NR = EZ * EY * EX;
    constexpr int PITCH = (IC == 8) ? 8 : IC + 8;
    constexpr int CHK = IC / 8;
    constexpr int KK = (27 * IC + 31) / 32;
    constexpr int NT = (OCR + 15) / 16;
    constexpr int MT = (TY * TX) / 16;
    constexpr int MROWS = 16 / TX;
    static_assert(TZ == 4, "wave = z-slice");
    static_assert(TPB % CHK == 0, "thread-fixed chunk");
    __shared__ __align__(16) bf16 si[NR * PITCH];
    __shared__ float ps[4][2 * 16 * NT];
    const int ntx = OW / TX, nty = OH / TY;
    const int bx = blockIdx.x % ntx;
    const int by = (blockIdx.x / ntx) % nty;
    const int bz = blockIdx.x / (ntx * nty);
    const int x0 = bx * TX * STRIDE - 1;
    const int y0 = by * TY * STRIDE - 1;
    const int z0 = bz * TZ * STRIDE - 1;

    {
        const bf16* in = (const bf16*)in_;
        float sc[8], sh[8];
        if constexpr (BNIN)
            bnco(bst, bg, bb, binvN, (threadIdx.x % CHK) * 8, sc, sh);
        for (int i = threadIdx.x; i < NR * CHK; i += TPB) {
            int r = i / CHK, c = i % CHK;
            int rx = r % EX, ry = (r / EX) % EY, rz = r / (EX * EY);
            int gz = z0 + rz, gy = y0 + ry, gx = x0 + rx;
            bool ok = (unsigned)gz < (unsigned)ID && (unsigned)gy < (unsigned)IH &&
                      (unsigned)gx < (unsigned)IW;
            uint4 u = make_uint4(0u, 0u, 0u, 0u);
            if (ok)
                u = *(const uint4*)(in + (((long)gz * IH + gy) * IW + gx) * CSin + c * 8);
            if constexpr (BNIN) {
                bf16 o[8];
                if (ok) bnap(u, sc, sh, o);
                else {
#pragma unroll
                    for (int j = 0; j < 8; ++j) o[j] = __float2bfloat16(0.f);
                }
                *(uint4*)(si + r * PITCH + c * 8) = *(const uint4*)o;
            } else {
                *(uint4*)(si + r * PITCH + c * 8) = u;
            }
        }
    }
    __syncthreads();

    const int w = threadIdx.x >> 6;     // z-slice within tile
    const int lane = threadIdx.x & 63;
    const int q = lane >> 4, m = lane & 15;
    const int vy = m / TX, vx = m % TX;

    f4v acc[MT][NT];
#pragma unroll
    for (int mt = 0; mt < MT; ++mt)
#pragma unroll
        for (int nt = 0; nt < NT; ++nt) acc[mt][nt] = (f4v)(0.f);

#define KBODY                                                                  \
    {                                                                          \
        int flat = kk * 32 + q * 8;                                            \
        int tb = flat / IC; if (tb > 26) tb = 26;                              \
        const int cb = flat % IC;                                              \
        const int kz = tb / 9, ky = (tb / 3) % 3, kx = tb % 3;                 \
        s8v bfr[NT];                                                           \
        _Pragma("unroll")                                                      \
        for (int nt = 0; nt < NT; ++nt)                                        \
            bfr[nt] = *(const s8v*)(wb + ((long)(kk * NT + nt) << 9) + lane * 8); \
        const int iz = w * STRIDE + kz;                                        \
        const int ixc = vx * STRIDE + kx;                                      \
        _Pragma("unroll")                                                      \
        for (int mt = 0; mt < MT; ++mt) {                                      \
            int iy = (mt * MROWS + vy) * STRIDE + ky;                          \
            int row = (iz * EY + iy) * EX + ixc;                               \
            s8v av = *(const s8v*)(si + row * PITCH + cb);                     \
            _Pragma("unroll")                                                  \
            for (int nt = 0; nt < NT; ++nt)                                    \
                acc[mt][nt] = __builtin_amdgcn_mfma_f32_16x16x32_bf16(         \
                    av, bfr[nt], acc[mt][nt], 0, 0, 0);                        \
        }                                                                      \
    }

    if constexpr (KK <= 7) {
#pragma unroll
        for (int kk = 0; kk < KK; ++kk) KBODY
    } else {
#pragma unroll 1
        for (int kk = 0; kk < KK; ++kk) KBODY
    }
#undef KBODY

    // epilogue: store + stats (stats are over the RAW output)
    float ls[NT], ls2[NT];
#pragma unroll
    for (int nt = 0; nt < NT; ++nt) { ls[nt] = 0.f; ls2[nt] = 0.f; }
    const int oz = bz * TZ + w;
#pragma unroll
    for (int mt = 0; mt < MT; ++mt)
#pragma unroll
        for (int nt = 0; nt < NT; ++nt) {
            const int n_ch = nt * 16 + m;
            if constexpr (DOSTATS) {
#pragma unroll
                for (int r = 0; r < 4; ++r) {
                    float v = acc[mt][nt][r];
                    ls[nt] += v; ls2[nt] += v * v;   // padded cols are exactly 0
                }
            }
            if (n_ch < OCR) {
#pragma unroll
                for (int r = 0; r < 4; ++r) {
                    int vrow = 4 * q + r;
                    int oy = by * TY + mt * MROWS + vrow / TX;
                    int ox = bx * TX + vrow % TX;
                    long vox = ((long)oz * OH + oy) * OW + ox;
                    if constexpr (CFOUT) {
                        long Sout = (long)OD * OH * OW;
                        outf[(long)n_ch * Sout + vox] = acc[mt][nt][r];
                    } else {
                        out[vox * CSout + n_ch] = __float2bfloat16(acc[mt][nt][r]);
                    }
                }
            }
        }
    if constexpr (DOSTATS) {
#pragma unroll
        for (int nt = 0; nt < NT; ++nt) {
            float t = ls[nt], t2 = ls2[nt];
            t  += __shfl_down(t, 32, 64);  t  += __shfl_down(t, 16, 64);
            t2 += __shfl_down(t2, 32, 64); t2 += __shfl_down(t2, 16, 64);
            if (lane < 16) {
                ps[w][2 * (nt * 16 + lane)]     = t;
                ps[w][2 * (nt * 16 + lane) + 1] = t2;
            }
        }
        __syncthreads();
        if (threadIdx.x < 2 * OCR) {
            float v = ps[0][threadIdx.x] + ps[1][threadIdx.x]
                    + ps[2][threadIdx.x] + ps[3][threadIdx.x];
            prt[(long)threadIdx.x * nrow + blockIdx.x] = v;
        }
    }
}

// ---------------------------------------------------------------------------
// Specialized final conv (round-11 proven, ~106-114us): cat1 [128^3][24] raw +
// s1 [128^3][8] raw -> d_out fp32 CF [2][128^3]. BN of BOTH inputs fused in
// staging. Tile 4x8x8, PITCH=32 (38.4KB LDS, 4 blocks/CU, 52 VGPR no spill),
// compact B wc[tap][2][32] (n = m&1), kz/kx fully unrolled.
// ---------------------------------------------------------------------------
__global__ __launch_bounds__(TPB, 4) void outconv_k(
    const bf16* __restrict__ cat, const bf16* __restrict__ s1v,
    const bf16* __restrict__ wc, float* __restrict__ outf,
    const float* __restrict__ stats, const float* __restrict__ g,
    const float* __restrict__ b,
    const float* __restrict__ stS, const float* __restrict__ gS,
    const float* __restrict__ bS, float invN)
{
    constexpr int EY = 10, EX = 10, PITCH = 32;
    __shared__ __align__(16) bf16 si[600 * PITCH];
    const int bx = blockIdx.x & 15;
    const int by = (blockIdx.x >> 4) & 15;
    const int bz = blockIdx.x >> 8;
    const int x0 = bx * 8 - 1, y0 = by * 8 - 1, z0 = bz * 4 - 1;

    const int c4 = threadIdx.x & 3;
    float sc[8], sh[8];
    if (c4 < 3) bnco(stats, g, b, invN, c4 * 8, sc, sh);
    else        bnco(stS, gS, bS, invN, 0, sc, sh);

    const int col = threadIdx.x >> 2;   // 0..63
    const bool inter = (bx > 0) & (bx < 15) & (by > 0) & (by < 15) &
                       (bz > 0) & (bz < 31);
#pragma unroll
    for (int cp = 0; cp < 2; ++cp) {
        const int cc = col + cp * 64;
        if (cc < 100) {
            const int ry = cc / 10, rx = cc - ry * 10;
            const int gy = y0 + ry, gx = x0 + rx;
            const long vyx = (long)gy * 128 + gx;
            uint4 u[6];
            if (inter) {
#pragma unroll
                for (int rz = 0; rz < 6; ++rz) {
                    long vox = ((long)(z0 + rz) << 14) + vyx;
                    const bf16* p = (c4 == 3) ? (s1v + vox * 8)
                                              : (cat + vox * 24 + c4 * 8);
                    u[rz] = *(const uint4*)p;
                }
#pragma unroll
                for (int rz = 0; rz < 6; ++rz) {
                    bf16 o[8];
                    bnap(u[rz], sc, sh, o);
                    *(uint4*)(si + (rz * 100 + cc) * PITCH + c4 * 8) =
                        *(const uint4*)o;
                }
            } else {
                const bool yxok = ((unsigned)gy < 128u) & ((unsigned)gx < 128u);
                unsigned zm = 0u;
#pragma unroll
                for (int rz = 0; rz < 6; ++rz) {
                    u[rz] = make_uint4(0u, 0u, 0u, 0u);
                    int gz = z0 + rz;
                    if (yxok && (unsigned)gz < 128u) {
                        long vox = ((long)gz << 14) + vyx;
                        const bf16* p = (c4 == 3) ? (s1v + vox * 8)
                                                  : (cat + vox * 24 + c4 * 8);
                        u[rz] = *(const uint4*)p;
                        zm |= 1u << rz;
                    }
                }
#pragma unroll
                for (int rz = 0; rz < 6; ++rz) {
                    bf16 o[8];
                    if ((zm >> rz) & 1u) bnap(u[rz], sc, sh, o);
                    else {
#pragma unroll
                        for (int j = 0; j < 8; ++j) o[j] = __float2bfloat16(0.f);
                    }
                    *(uint4*)(si + (rz * 100 + cc) * PITCH + c4 * 8) =
                        *(const uint4*)o;
                }
            }
        }
    }
    __syncthreads();

    const int w = threadIdx.x >> 6;
    const int lane = threadIdx.x & 63;
    const int q = lane >> 4, m = lane & 15;
    const int vy = (m >> 3) & 1, vx = m & 7;

    f4v acc[4];
#pragma unroll
    for (int mt = 0; mt < 4; ++mt) acc[mt] = (f4v)(0.f);

    const bf16* wcl = wc + (m & 1) * 32 + q * 8;   // + tap*64
#pragma unroll
    for (int kz = 0; kz < 3; ++kz) {
#pragma unroll
        for (int kx = 0; kx < 3; ++kx) {
            const bf16* sp = si +
                ((((w + kz) * EY + vy) * EX) + vx + kx) * PITCH + q * 8;
            s8v a[9];
#pragma unroll
            for (int j = 0; j < 9; ++j)
                a[j] = *(const s8v*)(sp + j * (EX * PITCH));
            const bf16* bp = wcl + (kz * 9 + kx) * 64;
            s8v bf0 = *(const s8v*)(bp);            // ky=0
            s8v bf1 = *(const s8v*)(bp + 3 * 64);   // ky=1
            s8v bf2 = *(const s8v*)(bp + 6 * 64);   // ky=2
#pragma unroll
            for (int mt = 0; mt < 4; ++mt) {
                acc[mt] = __builtin_amdgcn_mfma_f32_16x16x32_bf16(
                    a[2 * mt + 0], bf0, acc[mt], 0, 0, 0);
                acc[mt] = __builtin_amdgcn_mfma_f32_16x16x32_bf16(
                    a[2 * mt + 1], bf1, acc[mt], 0, 0, 0);
                acc[mt] = __builtin_amdgcn_mfma_f32_16x16x32_bf16(
                    a[2 * mt + 2], bf2, acc[mt], 0, 0, 0);
            }
        }
    }
    if (m < 2) {
        const long Sout = 128L * 128 * 128;
        const int oz = bz * 4 + w;
#pragma unroll
        for (int mt = 0; mt < 4; ++mt) {
#pragma unroll
            for (int r = 0; r < 4; ++r) {
                int vrow = 4 * q + r;
                int oy = by * 8 + mt * 2 + (vrow >> 3);
                int ox = bx * 8 + (vrow & 7);
                outf[(long)m * Sout + (((long)oz * 128 + oy) * 128 + ox)] =
                    acc[mt][r];
            }
        }
    }
}

// ---------------------------------------------------------------------------
// MFMA transposed conv, stride 2, k=3. BN+ReLU of the (raw) input fused into
// staging (thread-fixed chunk). Channels < C0 use stat group 0, >= C0 group 1.
// PITCH = 64 for IC=48, 72 for IC=64.
// ---------------------------------------------------------------------------
template <int IC, int OCR>
__global__ __launch_bounds__(TPB) void tconv_mfma_k(
    const bf16* __restrict__ in, const bf16* __restrict__ wb,
    bf16* __restrict__ out, int ID, int IH, int IW, int CSin, int CSout,
    float* __restrict__ prt, int nrow,
    const float* __restrict__ st0, const float* __restrict__ g0p,
    const float* __restrict__ b0p, const float* __restrict__ st1,
    const float* __restrict__ g1p, const float* __restrict__ b1p,
    float binvN, int C0)
{
    constexpr int KC = (IC + 31) / 32;
    constexpr int NT = (OCR + 15) / 16;
    constexpr int TZ = 4, TY = 4, TX = 8;
    constexpr int EZ = TZ + 1, EY = TY + 1, EX = TX + 1;
    constexpr int NR = EZ * EY * EX;
    constexpr int PITCH = (IC == 48) ? 64 : 72;
    constexpr int CHKS = 8;
    constexpr int CHK = IC / 8;
    __shared__ __align__(16) bf16 si[NR * PITCH];
    __shared__ float ps[4][64];
    const int ntx = IW / TX, nty = IH / TY;
    const int bx = blockIdx.x % ntx;
    const int by = (blockIdx.x / ntx) % nty;
    const int bz = blockIdx.x / (ntx * nty);
    const int x0 = bx * TX, y0 = by * TY, z0 = bz * TZ;

    // per-thread BN coeffs for fixed chunk c = tid & 7
    {
        const int c = threadIdx.x & 7;
        float sc[8], sh[8];
#pragma unroll
        for (int j = 0; j < 8; ++j) { sc[j] = 1.f; sh[j] = 0.f; }
        if (c < CHK) {
#pragma unroll
            for (int j = 0; j < 8; ++j) {
                int ch = c * 8 + j;
                const float* st; const float* gg; const float* bbq; int k;
                if (ch < C0) { st = st0; gg = g0p; bbq = b0p; k = ch; }
                else         { st = st1; gg = g1p; bbq = b1p; k = ch - C0; }
                float mean = st[2 * k] * binvN;
                float var  = st[2 * k + 1] * binvN - mean * mean;
                sc[j] = rsqrtf(var + 1e-5f) * gg[k];
                sh[j] = bbq[k] - mean * sc[j];
            }
        }
        for (int i = threadIdx.x; i < NR * CHKS; i += TPB) {
            int r = i >> 3, cc = i & 7;
            int rx = r % EX, ry = (r / EX) % EY, rz = r / (EX * EY);
            int gz = z0 + rz, gy = y0 + ry, gx = x0 + rx;
            bool ok = (cc < CHK) && gz < ID && gy < IH && gx < IW;
            uint4 u = make_uint4(0u, 0u, 0u, 0u);
            if (ok)
                u = *(const uint4*)(in + (((long)gz * IH + gy) * IW + gx) * CSin + cc * 8);
            bf16 o[8];
            if (ok) bnap(u, sc, sh, o);
            else {
#pragma unroll
                for (int j = 0; j < 8; ++j) o[j] = __float2bfloat16(0.f);
            }
            *(uint4*)(si + r * PITCH + cc * 8) = *(const uint4*)o;
        }
    }
    __syncthreads();
    const int w = threadIdx.x >> 6;
    const int lane = threadIdx.x & 63;
    const int q = lane >> 4, m = lane & 15;
    const int vy = m >> 3, vx = m & 7;
    const int OH = 2 * IH, OW = 2 * IW;
    float ls[NT], ls2[NT];
#pragma unroll
    for (int nt = 0; nt < NT; ++nt) { ls[nt] = 0.f; ls2[nt] = 0.f; }

#pragma unroll 1
    for (int cls = 0; cls < 8; ++cls) {
        const int pz = (cls >> 2) & 1, py = (cls >> 1) & 1, px = cls & 1;
        const int ny = 1 + py, nx = 1 + px;
        const int ntap = (1 + pz) * ny * nx;
        f4v acc[2][NT];
#pragma unroll
        for (int mt = 0; mt < 2; ++mt)
#pragma unroll
            for (int nt = 0; nt < NT; ++nt) acc[mt][nt] = (f4v)(0.f);
#pragma unroll 1
        for (int s = 0; s < ntap; ++s) {
            int a = s / (ny * nx), b = (s / nx) % ny, cc = s % nx;
            int dz = pz ? a : 0, dy = py ? b : 0, dx = px ? cc : 0;
            int kz = pz ? (a ? 2 : 0) : 1;
            int ky = py ? (b ? 2 : 0) : 1;
            int kx = px ? (cc ? 2 : 0) : 1;
            int kt = kz * 9 + ky * 3 + kx;
#pragma unroll
            for (int kc = 0; kc < KC; ++kc) {
                const bf16* bp = wb + (long)((kt * KC + kc) * NT) * 512 + lane * 8;
                s8v b0 = *(const s8v*)bp;
                s8v b1 = *(const s8v*)(bp + 512);
#pragma unroll
                for (int mt = 0; mt < 2; ++mt) {
                    int row = ((w + dz) * EY + (2 * mt + vy + dy)) * EX + (vx + dx);
                    s8v av = *(const s8v*)(si + row * PITCH + kc * 32 + q * 8);
                    acc[mt][0] = __builtin_amdgcn_mfma_f32_16x16x32_bf16(
                        av, b0, acc[mt][0], 0, 0, 0);
                    acc[mt][1] = __builtin_amdgcn_mfma_f32_16x16x32_bf16(
                        av, b1, acc[mt][1], 0, 0, 0);
                }
            }
        }
        const int z = 2 * (z0 + w) + pz;
#pragma unroll
        for (int mt = 0; mt < 2; ++mt)
#pragma unroll
            for (int nt = 0; nt < NT; ++nt) {
                const int n_ch = nt * 16 + m;
#pragma unroll
                for (int r = 0; r < 4; ++r) {
                    float v = acc[mt][nt][r];
                    ls[nt] += v; ls2[nt] += v * v;
                }
                if (n_ch < OCR) {
#pragma unroll
                    for (int r = 0; r < 4; ++r) {
                        int vrow = 4 * q + r;
                        int yy = 2 * (y0 + 2 * mt + (vrow >> 3)) + py;
                        int xx = 2 * (x0 + (vrow & 7)) + px;
                        out[(((long)z * OH + yy) * OW + xx) * CSout + n_ch] =
                            __float2bfloat16(acc[mt][nt][r]);
                    }
                }
            }
    }
#pragma unroll
    for (int nt = 0; nt < NT; ++nt) {
        float t = ls[nt], t2 = ls2[nt];
        t  += __shfl_down(t, 32, 64);  t  += __shfl_down(t, 16, 64);
        t2 += __shfl_down(t2, 32, 64); t2 += __shfl_down(t2, 16, 64);
        if (lane < 16) {
            ps[w][2 * (nt * 16 + lane)]     = t;
            ps[w][2 * (nt * 16 + lane) + 1] = t2;
        }
    }
    __syncthreads();
    if (threadIdx.x < 2 * OCR) {
        float v = ps[0][threadIdx.x] + ps[1][threadIdx.x] + ps[2][threadIdx.x]
                + ps[3][threadIdx.x];
        prt[(long)threadIdx.x * nrow + blockIdx.x] = v;
    }
}

extern "C" void kernel_launch(void* const* d_in, const int* in_sizes, int n_in,
                              void* d_out, int out_size, void* d_ws, size_t ws_size,
                              hipStream_t stream)
{
    const float* x    = (const float*)d_in[0];
    const float* w0   = (const float*)d_in[1];
    const float* g0   = (const float*)d_in[2];
    const float* b0   = (const float*)d_in[3];
    const float* w1   = (const float*)d_in[4];
    const float* g1   = (const float*)d_in[5];
    const float* b1   = (const float*)d_in[6];
    const float* w2   = (const float*)d_in[7];
    const float* g2   = (const float*)d_in[8];
    const float* b2   = (const float*)d_in[9];
    const float* w3   = (const float*)d_in[10];
    const float* g3   = (const float*)d_in[11];
    const float* b3   = (const float*)d_in[12];
    const float* wt3  = (const float*)d_in[13];
    const float* gt3  = (const float*)d_in[14];
    const float* bt3  = (const float*)d_in[15];
    const float* wt2  = (const float*)d_in[16];
    const float* gt2  = (const float*)d_in[17];
    const float* bt2  = (const float*)d_in[18];
    const float* wt1  = (const float*)d_in[19];
    const float* gt1  = (const float*)d_in[20];
    const float* bt1  = (const float*)d_in[21];
    const float* wout = (const float*)d_in[22];

    const long S128 = 128L * 128 * 128;
    const long S64  = 64L * 64 * 64;
    const long S32  = 32L * 32 * 32;
    const long S16  = 16L * 16 * 16;

    // ---- d_ws: stats | wc | activations (ALL raw; BN fused into consumers)
    float* stats = (float*)d_ws;                       // 512 floats
    bf16*  wc    = (bf16*)((char*)d_ws + 2048);        // 1728 bf16 (slot 27648 B)
    bf16* base = (bf16*)((char*)d_ws + 2048 + 27648);
    bf16* cat1 = base;                 // [128^3][24]: tconv1 out (raw)
    bf16* cat2 = cat1 + S128 * 24;     // [64^3][48] : ch0-31 tconv2 raw, ch32-47 s2 raw
    bf16* cat3 = cat2 + S64 * 48;      // [32^3][64] : ch0-31 tconv3 raw, ch32-63 s4 raw
    bf16* s8   = cat3 + S32 * 64;      // [16^3][64] raw
    bf16* s1   = s8 + S16 * 64;        // [128^3][8] raw
    bf16* s2 = cat2 + 32;
    bf16* s4 = cat3 + 32;
    // s0 (transposed input, bf16 CL [128^3][8]) aliases the cat1 region:
    // consumed by conv0 long before tconv1 writes cat1.
    bf16* s0 = cat1;

    // ---- d_out scratch (all consumed before the final out-conv writes) ----
    bf16*  wbb  = (bf16*)d_out;
    bf16*  wbt1 = wbb;                  // 55296
    bf16*  wbt2 = wbb + 55296;          // 55296
    bf16*  wbt3 = wbb + 110592;         // 55296
    bf16*  wb0  = wbb + 165888;         // 3584
    bf16*  wb1  = wbb + 169472;         // 3584
    bf16*  wb2  = wbb + 173056;         // 14336
    bf16*  wb3  = wbb + 187392;         // 55296 (ends 242688 = 485 KB)
    float* prt  = (float*)d_out + 524288;  // partials, col-major (2 MB offset)

    // One init dispatch: all 8 weight repacks (955 blocks).
    init_all_k<<<955, TPB, 0, stream>>>(
        wt1, wt2, wt3, w0, w1, w2, w3, wout,
        wbt1, wbt2, wbt3, wb0, wb1, wb2, wb3, wc);

    // transpose x: fp32 CF -> bf16 CL (kills conv0's CF gather over-fetch).
    xpose_k<<<8192, TPB, 0, stream>>>(x, s0);

    // ---- encoder (all outputs raw; stats via prt+sumcol; no bnrelu passes)
    // conv0: s0 CL [128^3][8] -> s1 raw. 8192 blocks.
    conv_mfma_k<8, 8, 1, 4, 8, 8, false, true, false><<<8192, TPB, 0, stream>>>(
        s0, wb0, s1, nullptr, 128, 128, 128, 128, 128, 128, 8, 8, prt, 8192,
        nullptr, nullptr, nullptr, 0.f);
    sumcol_k<<<16, TPB, 0, stream>>>(prt, 8192, stats + 0);

    // conv1: s1 raw (BN g0/b0 in staging) -> s2 raw. 1024 blocks.
    conv_mfma_k<8, 16, 2, 4, 8, 8, false, true, true><<<1024, TPB, 0, stream>>>(
        s1, wb1, s2, nullptr, 128, 128, 128, 64, 64, 64, 8, 48, prt, 1024,
        stats + 0, g0, b0, 1.f / S128);
    sumcol_k<<<32, TPB, 0, stream>>>(prt, 1024, stats + 16);

    // conv2: s2 raw (BN g1/b1) -> s4 raw. 512 blocks.
    conv_mfma_k<16, 32, 2, 4, 4, 4, false, true, true><<<512, TPB, 0, stream>>>(
        s2, wb2, s4, nullptr, 64, 64, 64, 32, 32, 32, 48, 64, prt, 512,
        stats + 16, g1, b1, 1.f / S64);
    sumcol_k<<<64, TPB, 0, stream>>>(prt, 512, stats + 48);

    // conv3: s4 raw (BN g2/b2) -> s8 raw. 64 blocks.
    conv_mfma_k<32, 64, 2, 4, 4, 4, false, true, true><<<64, TPB, 0, stream>>>(
        s4, wb3, s8, nullptr, 32, 32, 32, 16, 16, 16, 64, 64, prt, 64,
        stats + 48, g2, b2, 1.f / S32);
    sumcol_k<<<128, TPB, 0, stream>>>(prt, 64, stats + 112);

    // ---- decoder ----
    // tconv3: s8 raw (BN g3/b3, all 64ch) -> cat3 ch0-31 raw. 32 blocks.
    tconv_mfma_k<64, 32><<<32, TPB, 0, stream>>>(
        s8, wbt3, cat3, 16, 16, 16, 64, 64, prt, 32,
        stats + 112, g3, b3, stats + 112, g3, b3, 1.f / S16, 64);
    sumcol_k<<<64, TPB, 0, stream>>>(prt, 32, stats + 240);

    // tconv2: cat3 (ch0-31 BN gt3/bt3, ch32-63 BN g2/b2) -> cat2 ch0-31 raw.
    tconv_mfma_k<64, 32><<<256, TPB, 0, stream>>>(
        cat3, wbt2, cat2, 32, 32, 32, 64, 48, prt, 256,
        stats + 240, gt3, bt3, stats + 48, g2, b2, 1.f / S32, 32);
    sumcol_k<<<64, TPB, 0, stream>>>(prt, 256, stats + 304);

    // tconv1: cat2 (ch0-31 BN gt2/bt2, ch32-47 BN g1/b1) -> cat1 raw
    // (overwrites the dead s0 alias). 2048 blocks.
    tconv_mfma_k<48, 24><<<2048, TPB, 0, stream>>>(
        cat2, wbt1, cat1, 64, 64, 64, 48, 24, prt, 2048,
        stats + 304, gt2, bt2, stats + 16, g1, b1, 1.f / S64, 32);
    sumcol_k<<<48, TPB, 0, stream>>>(prt, 2048, stats + 368);

    // out conv: cat1 raw (BN gt1/bt1) + s1 raw (BN g0/b0) -> d_out fp32 [2][128^3].
    outconv_k<<<8192, TPB, 0, stream>>>(
        cat1, s1, wc, (float*)d_out, stats + 368, gt1, bt1,
        stats + 0, g0, b0, 1.f / S128);
}